// Round 1
// baseline (8803.804 us; speedup 1.0000x reference)
//
#include <hip/hip_runtime.h>

// D = 64 fixed throughout (16 float4 per row).

__global__ __launch_bounds__(256) void k_embed(const float* __restrict__ emb,
                                               const int* __restrict__ sp,
                                               float* __restrict__ x,
                                               int n_nodes, int n_species) {
  int t = blockIdx.x * 256 + threadIdx.x;
  int node = t >> 4, q = t & 15;
  if (node >= n_nodes) return;
  int s = sp[node];
  int row = (s < 0) ? n_species : s;
  reinterpret_cast<float4*>(x)[node * 16 + q] =
      reinterpret_cast<const float4*>(emb)[row * 16 + q];
}

__global__ __launch_bounds__(256) void k_scatter(const float* __restrict__ x,
                                                 float* __restrict__ msg,
                                                 const int* __restrict__ src,
                                                 const int* __restrict__ dst,
                                                 int nE) {
  int t = blockIdx.x * 256 + threadIdx.x;
  int e = t >> 4, q = t & 15;
  if (e >= nE) return;
  int s = src[e], d = dst[e];
  float4 v = reinterpret_cast<const float4*>(x)[s * 16 + q];
  float* m = msg + (size_t)d * 64 + q * 4;
  atomicAdd(m + 0, v.x);
  atomicAdd(m + 1, v.y);
  atomicAdd(m + 2, v.z);
  atomicAdd(m + 3, v.w);
}

// One wave (64 lanes) per node: u=(1+eps)x+msg; t=relu(uW1+b1); h=tW2+b2;
// out = LN(x+h)*g+b. W1/W2 staged in LDS; mat-vec via __shfl broadcast.
__global__ __launch_bounds__(256) void k_mlp(const float* __restrict__ x_in,
                                             const float* __restrict__ msg,
                                             const float* __restrict__ W1,
                                             const float* __restrict__ b1,
                                             const float* __restrict__ W2,
                                             const float* __restrict__ b2,
                                             const float* __restrict__ eps_p,
                                             const float* __restrict__ gam,
                                             const float* __restrict__ bet,
                                             float* __restrict__ x_out, int n) {
  __shared__ float sW1[64 * 64];
  __shared__ float sW2[64 * 64];
  __shared__ float sb1[64], sb2[64], sg[64], sb[64];
  int tid = threadIdx.x;
  for (int i = tid; i < 4096; i += 256) {
    sW1[i] = W1[i];
    sW2[i] = W2[i];
  }
  if (tid < 64) {
    sb1[tid] = b1[tid];
    sb2[tid] = b2[tid];
    sg[tid] = gam[tid];
    sb[tid] = bet[tid];
  }
  __syncthreads();
  int wave = tid >> 6, lane = tid & 63;
  int node = blockIdx.x * 4 + wave;
  if (node >= n) return;
  float e1 = 1.0f + eps_p[0];
  float xv = x_in[(size_t)node * 64 + lane];
  float u = e1 * xv + msg[(size_t)node * 64 + lane];
  float t = sb1[lane];
#pragma unroll 8
  for (int k = 0; k < 64; ++k) {
    float uk = __shfl(u, k);
    t = fmaf(uk, sW1[k * 64 + lane], t);
  }
  t = fmaxf(t, 0.0f);
  float h = sb2[lane];
#pragma unroll 8
  for (int k = 0; k < 64; ++k) {
    float tk = __shfl(t, k);
    h = fmaf(tk, sW2[k * 64 + lane], h);
  }
  float y = xv + h;
  float s = y;
  for (int off = 32; off; off >>= 1) s += __shfl_xor(s, off);
  float mu = s * (1.0f / 64.0f);
  float d0 = y - mu;
  float v = d0 * d0;
  for (int off = 32; off; off >>= 1) v += __shfl_xor(v, off);
  v *= (1.0f / 64.0f);
  float outv = d0 * rsqrtf(v + 1e-5f) * sg[lane] + sb[lane];
  x_out[(size_t)node * 64 + lane] = outv;
}

__global__ __launch_bounds__(256) void k_pool(const float* __restrict__ x,
                                              const int* __restrict__ sp,
                                              const int* __restrict__ leaf,
                                              const int* __restrict__ batch,
                                              float* __restrict__ sums,
                                              float* __restrict__ cnts,
                                              int n_nodes, int n_species) {
  int t = blockIdx.x * 256 + threadIdx.x;
  int node = t >> 4, q = t & 15;
  if (node >= n_nodes) return;
  int s = sp[node];
  if (s < 0 || !leaf[node]) return;
  int comp = batch[node] * n_species + s;
  float4 v = reinterpret_cast<const float4*>(x)[node * 16 + q];
  float* p = sums + (size_t)comp * 64 + q * 4;
  atomicAdd(p + 0, v.x);
  atomicAdd(p + 1, v.y);
  atomicAdd(p + 2, v.z);
  atomicAdd(p + 3, v.w);
  if (q == 0) atomicAdd(cnts + comp, 1.0f);
}

__global__ __launch_bounds__(256) void k_norm(float* __restrict__ sums,
                                              const float* __restrict__ cnts,
                                              int pool_n) {
  int t = blockIdx.x * 256 + threadIdx.x;
  int comp = t >> 4, q = t & 15;
  if (comp >= pool_n) return;
  float c = cnts[comp];
  float sc = 1.0f / fmaxf(c, 1.0f);
  float4 v = reinterpret_cast<float4*>(sums)[comp * 16 + q];
  v.x *= sc; v.y *= sc; v.z *= sc; v.w *= sc;
  reinterpret_cast<float4*>(sums)[comp * 16 + q] = v;
}

// One block per species-tree edge. 4 waves stride over gene trees;
// lane = feature dim. Sum / sum-of-squares accumulation, LDS cross-wave reduce.
__global__ __launch_bounds__(256) void k_edge(const float* __restrict__ pool,
                                              const float* __restrict__ cnts,
                                              const int* __restrict__ clade_mask,
                                              float* __restrict__ out,
                                              int n_gt, int n_species) {
  __shared__ int slist[256];
  __shared__ int scount;
  __shared__ float red1[4][64];
  __shared__ float red2[4][64];
  __shared__ float redn[4];
  int e = blockIdx.x;
  int tid = threadIdx.x, lane = tid & 63, w = tid >> 6;
  if (tid == 0) {
    int c = 0;
    for (int s = 0; s < n_species; ++s)
      if (clade_mask[(size_t)e * n_species + s]) slist[c++] = s;
    scount = c;
  }
  __syncthreads();
  int nc = scount;
  float S1 = 0.f, S2 = 0.f, nv = 0.f;
  for (int g = w; g < n_gt; g += 4) {
    const float* poolg = pool + (size_t)g * n_species * 64;
    const float* cntg = cnts + (size_t)g * n_species;
    float csum = 0.f;
    int ccnt = 0;
    for (int i = 0; i < nc; ++i) {
      int s = slist[i];
      float c = cntg[s];
      if (c > 0.f) {
        ccnt += 1;
        csum += poolg[s * 64 + lane];
      }
    }
    if (ccnt > 0) {
      float gm = csum / (float)ccnt;
      S1 += gm;
      S2 += gm * gm;
      nv += 1.f;
    }
  }
  red1[w][lane] = S1;
  red2[w][lane] = S2;
  if (lane == 0) redn[w] = nv;
  __syncthreads();
  if (w == 0) {
    float s1 = red1[0][lane] + red1[1][lane] + red1[2][lane] + red1[3][lane];
    float s2 = red2[0][lane] + red2[1][lane] + red2[2][lane] + red2[3][lane];
    float n_v = redn[0] + redn[1] + redn[2] + redn[3];
    float mean = (n_v > 0.f) ? s1 / n_v : 0.f;
    float var = (s2 - s1 * s1 / fmaxf(n_v, 1.f)) / fmaxf(n_v - 1.f, 1.f);
    float stdv = (n_v > 1.f) ? sqrtf(fmaxf(var, 0.f)) : 0.f;
    out[(size_t)e * 128 + lane] = mean;
    out[(size_t)e * 128 + 64 + lane] = stdv;
  }
}

extern "C" void kernel_launch(void* const* d_in, const int* in_sizes, int n_in,
                              void* d_out, int out_size, void* d_ws, size_t ws_size,
                              hipStream_t stream) {
  (void)n_in; (void)out_size; (void)ws_size;
  const int* edge_index = (const int*)d_in[0];
  const int* sp_ids = (const int*)d_in[1];
  const int* leaf_mask = (const int*)d_in[2];
  const int* batch_vec = (const int*)d_in[3];
  const int* clade_mask = (const int*)d_in[4];
  // d_in[5] = n_gt scalar (device); shapes are fixed for this problem.
  const float* emb = (const float*)d_in[6];
  const float* W1 = (const float*)d_in[7];
  const float* b1 = (const float*)d_in[8];
  const float* W2 = (const float*)d_in[9];
  const float* b2 = (const float*)d_in[10];
  const float* eps = (const float*)d_in[11];
  const float* lng = (const float*)d_in[12];
  const float* lnb = (const float*)d_in[13];
  float* out = (float*)d_out;

  const int n_nodes = in_sizes[1];             // 204288
  const int nE = in_sizes[0] / 2;              // 407552
  const int n_species = in_sizes[6] / 64 - 1;  // 200
  const int n_edges = in_sizes[4] / n_species; // 397
  const int L = in_sizes[11];                  // 2
  const int n_gt = 512;                        // fixed problem size

  float* x = (float*)d_ws;
  size_t xb = (size_t)n_nodes * 64 * sizeof(float);
  float* msg = (float*)((char*)d_ws + xb);
  float* sums = msg;  // reused after GNN layers
  size_t poolb = (size_t)n_gt * n_species * 64 * sizeof(float);
  float* cnts = (float*)((char*)d_ws + xb + poolb);
  size_t cntb = (size_t)n_gt * n_species * sizeof(float);

  int embBlocks = (n_nodes * 16 + 255) / 256;
  k_embed<<<embBlocks, 256, 0, stream>>>(emb, sp_ids, x, n_nodes, n_species);

  for (int l = 0; l < L; ++l) {
    hipMemsetAsync(msg, 0, xb, stream);
    int scB = (nE * 16 + 255) / 256;
    k_scatter<<<scB, 256, 0, stream>>>(x, msg, edge_index, edge_index + nE, nE);
    int mlB = (n_nodes + 3) / 4;
    k_mlp<<<mlB, 256, 0, stream>>>(x, msg, W1 + l * 4096, b1 + l * 64,
                                   W2 + l * 4096, b2 + l * 64, eps + l,
                                   lng + l * 64, lnb + l * 64, x, n_nodes);
  }

  hipMemsetAsync(sums, 0, poolb + cntb, stream);
  k_pool<<<embBlocks, 256, 0, stream>>>(x, sp_ids, leaf_mask, batch_vec, sums,
                                        cnts, n_nodes, n_species);
  int pn = n_gt * n_species;
  k_norm<<<(pn * 16 + 255) / 256, 256, 0, stream>>>(sums, cnts, pn);
  k_edge<<<n_edges, 256, 0, stream>>>(sums, cnts, clade_mask, out, n_gt,
                                      n_species);
}

// Round 2
// 2006.513 us; speedup vs baseline: 4.3876x; 4.3876x over previous
//
#include <hip/hip_runtime.h>

// D = 64 fixed throughout (16 float4 per row).
#define SMAX 200

__global__ __launch_bounds__(256) void k_embed(const float* __restrict__ emb,
                                               const int* __restrict__ sp,
                                               float* __restrict__ x,
                                               int n_nodes, int n_species) {
  int t = blockIdx.x * 256 + threadIdx.x;
  int node = t >> 4, q = t & 15;
  if (node >= n_nodes) return;
  int s = sp[node];
  int row = (s < 0) ? n_species : s;
  reinterpret_cast<float4*>(x)[node * 16 + q] =
      reinterpret_cast<const float4*>(emb)[row * 16 + q];
}

__global__ __launch_bounds__(256) void k_scatter(const float* __restrict__ x,
                                                 float* __restrict__ msg,
                                                 const int* __restrict__ src,
                                                 const int* __restrict__ dst,
                                                 int nE) {
  int t = blockIdx.x * 256 + threadIdx.x;
  int e = t >> 4, q = t & 15;
  if (e >= nE) return;
  int s = src[e], d = dst[e];
  float4 v = reinterpret_cast<const float4*>(x)[s * 16 + q];
  float* m = msg + (size_t)d * 64 + q * 4;
  atomicAdd(m + 0, v.x);
  atomicAdd(m + 1, v.y);
  atomicAdd(m + 2, v.z);
  atomicAdd(m + 3, v.w);
}

// One wave (64 lanes) per node: u=(1+eps)x+msg; t=relu(uW1+b1); h=tW2+b2;
// out = LN(x+h)*g+b. W1/W2 staged in LDS; mat-vec via __shfl broadcast.
__global__ __launch_bounds__(256) void k_mlp(const float* __restrict__ x_in,
                                             const float* __restrict__ msg,
                                             const float* __restrict__ W1,
                                             const float* __restrict__ b1,
                                             const float* __restrict__ W2,
                                             const float* __restrict__ b2,
                                             const float* __restrict__ eps_p,
                                             const float* __restrict__ gam,
                                             const float* __restrict__ bet,
                                             float* __restrict__ x_out, int n) {
  __shared__ float sW1[64 * 64];
  __shared__ float sW2[64 * 64];
  __shared__ float sb1[64], sb2[64], sg[64], sb[64];
  int tid = threadIdx.x;
  for (int i = tid; i < 4096; i += 256) {
    sW1[i] = W1[i];
    sW2[i] = W2[i];
  }
  if (tid < 64) {
    sb1[tid] = b1[tid];
    sb2[tid] = b2[tid];
    sg[tid] = gam[tid];
    sb[tid] = bet[tid];
  }
  __syncthreads();
  int wave = tid >> 6, lane = tid & 63;
  int node = blockIdx.x * 4 + wave;
  if (node >= n) return;
  float e1 = 1.0f + eps_p[0];
  float xv = x_in[(size_t)node * 64 + lane];
  float u = e1 * xv + msg[(size_t)node * 64 + lane];
  float t = sb1[lane];
#pragma unroll 8
  for (int k = 0; k < 64; ++k) {
    float uk = __shfl(u, k);
    t = fmaf(uk, sW1[k * 64 + lane], t);
  }
  t = fmaxf(t, 0.0f);
  float h = sb2[lane];
#pragma unroll 8
  for (int k = 0; k < 64; ++k) {
    float tk = __shfl(t, k);
    h = fmaf(tk, sW2[k * 64 + lane], h);
  }
  float y = xv + h;
  float s = y;
  for (int off = 32; off; off >>= 1) s += __shfl_xor(s, off);
  float mu = s * (1.0f / 64.0f);
  float d0 = y - mu;
  float v = d0 * d0;
  for (int off = 32; off; off >>= 1) v += __shfl_xor(v, off);
  v *= (1.0f / 64.0f);
  float outv = d0 * rsqrtf(v + 1e-5f) * sg[lane] + sb[lane];
  x_out[(size_t)node * 64 + lane] = outv;
}

__global__ __launch_bounds__(256) void k_pool(const float* __restrict__ x,
                                              const int* __restrict__ sp,
                                              const int* __restrict__ leaf,
                                              const int* __restrict__ batch,
                                              float* __restrict__ sums,
                                              float* __restrict__ cnts,
                                              int n_nodes, int n_species) {
  int t = blockIdx.x * 256 + threadIdx.x;
  int node = t >> 4, q = t & 15;
  if (node >= n_nodes) return;
  int s = sp[node];
  if (s < 0 || !leaf[node]) return;
  int comp = batch[node] * n_species + s;
  float4 v = reinterpret_cast<const float4*>(x)[node * 16 + q];
  float* p = sums + (size_t)comp * 64 + q * 4;
  atomicAdd(p + 0, v.x);
  atomicAdd(p + 1, v.y);
  atomicAdd(p + 2, v.z);
  atomicAdd(p + 3, v.w);
  if (q == 0) atomicAdd(cnts + comp, 1.0f);
}

__global__ __launch_bounds__(256) void k_norm(float* __restrict__ sums,
                                              const float* __restrict__ cnts,
                                              int pool_n) {
  int t = blockIdx.x * 256 + threadIdx.x;
  int comp = t >> 4, q = t & 15;
  if (comp >= pool_n) return;
  float c = cnts[comp];
  float sc = 1.0f / fmaxf(c, 1.0f);
  float4 v = reinterpret_cast<float4*>(sums)[comp * 16 + q];
  v.x *= sc; v.y *= sc; v.z *= sc; v.w *= sc;
  reinterpret_cast<float4*>(sums)[comp * 16 + q] = v;
}

// Compact the clade mask into per-edge species lists via ballot/popcount.
__global__ __launch_bounds__(256) void k_slist(const int* __restrict__ clade,
                                               int* __restrict__ slist,
                                               int* __restrict__ scount,
                                               int n_edges, int n_species) {
  int wid = (blockIdx.x * 256 + threadIdx.x) >> 6;
  int lane = threadIdx.x & 63;
  if (wid >= n_edges) return;
  const int* row = clade + (size_t)wid * n_species;
  int base = 0;
  for (int b = 0; b < n_species; b += 64) {
    int idx = b + lane;
    bool pred = (idx < n_species) && (row[idx] != 0);
    unsigned long long m = __ballot(pred);
    int pos = __popcll(m & ((1ULL << lane) - 1ULL));
    if (pred) slist[(size_t)wid * SMAX + base + pos] = idx;
    base += __popcll(m);
  }
  if (lane == 0) scount[wid] = base;
}

// One block per gene tree g: pool[g] (200x64) + valid[g] staged in LDS.
// 8 waves stride over edges; clade species ids held in registers and
// shfl-broadcast; inner loop = shfl + ds_read + add (no global traffic).
__global__ __launch_bounds__(512) void k_gm(const float* __restrict__ pool,
                                            const float* __restrict__ cnts,
                                            const int* __restrict__ slist,
                                            const int* __restrict__ scount,
                                            float* __restrict__ gm_out,
                                            float* __restrict__ has_out,
                                            int n_edges, int n_species,
                                            int n_gt) {
  __shared__ float sPool[200 * 64];
  __shared__ float sValid[200];
  int g = blockIdx.x;
  int tid = threadIdx.x;
  const float* pg = pool + (size_t)g * n_species * 64;
  for (int i = tid; i < n_species * 64; i += 512) sPool[i] = pg[i];
  for (int i = tid; i < n_species; i += 512)
    sValid[i] = (cnts[(size_t)g * n_species + i] > 0.f) ? 1.f : 0.f;
  __syncthreads();
  int w = tid >> 6, lane = tid & 63;
  for (int e = w; e < n_edges; e += 8) {
    int nc = scount[e];
    const int* sl = slist + (size_t)e * SMAX;
    int r0 = (lane < nc) ? sl[lane] : 0;
    int r1 = (64 + lane < nc) ? sl[64 + lane] : 0;
    int r2 = (128 + lane < nc) ? sl[128 + lane] : 0;
    int r3 = (192 + lane < nc) ? sl[192 + lane] : 0;
    int c0 = min(nc, 64);
    int c1 = min(max(nc - 64, 0), 64);
    int c2 = min(max(nc - 128, 0), 64);
    int c3 = max(nc - 192, 0);
    float csum = 0.f;
#pragma unroll 4
    for (int i = 0; i < c0; ++i) {
      int s = __shfl(r0, i);
      csum += sPool[s * 64 + lane];
    }
#pragma unroll 4
    for (int i = 0; i < c1; ++i) {
      int s = __shfl(r1, i);
      csum += sPool[s * 64 + lane];
    }
#pragma unroll 4
    for (int i = 0; i < c2; ++i) {
      int s = __shfl(r2, i);
      csum += sPool[s * 64 + lane];
    }
    for (int i = 0; i < c3; ++i) {
      int s = __shfl(r3, i);
      csum += sPool[s * 64 + lane];
    }
    float cv = 0.f;
    if (lane < nc) cv += sValid[r0];
    if (64 + lane < nc) cv += sValid[r1];
    if (128 + lane < nc) cv += sValid[r2];
    if (192 + lane < nc) cv += sValid[r3];
    for (int off = 32; off; off >>= 1) cv += __shfl_xor(cv, off);
    float gm = csum / fmaxf(cv, 1.f);
    gm_out[((size_t)e * n_gt + g) * 64 + lane] = gm;
    if (lane == 0) has_out[(size_t)e * n_gt + g] = (cv > 0.f) ? 1.f : 0.f;
  }
}

// One block per species-tree edge: streaming mean/std over gene trees.
__global__ __launch_bounds__(512) void k_stat(const float* __restrict__ gmat,
                                              const float* __restrict__ has,
                                              float* __restrict__ out,
                                              int n_gt) {
  __shared__ float red1[8][64];
  __shared__ float red2[8][64];
  __shared__ float redn[8];
  int e = blockIdx.x;
  int tid = threadIdx.x, w = tid >> 6, lane = tid & 63;
  const float* ge = gmat + (size_t)e * n_gt * 64;
  const float* he = has + (size_t)e * n_gt;
  float S1 = 0.f, S2 = 0.f, nv = 0.f;
  for (int g = w; g < n_gt; g += 8) {
    float h = he[g];
    float v = ge[g * 64 + lane];
    S1 += h * v;
    S2 += h * v * v;
    nv += h;
  }
  red1[w][lane] = S1;
  red2[w][lane] = S2;
  if (lane == 0) redn[w] = nv;
  __syncthreads();
  if (w == 0) {
    float s1 = 0.f, s2 = 0.f, n_v = 0.f;
#pragma unroll
    for (int j = 0; j < 8; ++j) {
      s1 += red1[j][lane];
      s2 += red2[j][lane];
      n_v += redn[j];
    }
    float mean = s1 / fmaxf(n_v, 1.f);
    float var = (s2 - s1 * s1 / fmaxf(n_v, 1.f)) / fmaxf(n_v - 1.f, 1.f);
    float stdv = (n_v > 1.f) ? sqrtf(fmaxf(var, 0.f)) : 0.f;
    out[(size_t)e * 128 + lane] = (n_v > 0.f) ? mean : 0.f;
    out[(size_t)e * 128 + 64 + lane] = stdv;
  }
}

extern "C" void kernel_launch(void* const* d_in, const int* in_sizes, int n_in,
                              void* d_out, int out_size, void* d_ws, size_t ws_size,
                              hipStream_t stream) {
  (void)n_in; (void)out_size; (void)ws_size;
  const int* edge_index = (const int*)d_in[0];
  const int* sp_ids = (const int*)d_in[1];
  const int* leaf_mask = (const int*)d_in[2];
  const int* batch_vec = (const int*)d_in[3];
  const int* clade_mask = (const int*)d_in[4];
  // d_in[5] = n_gt scalar (device); shapes are fixed for this problem.
  const float* emb = (const float*)d_in[6];
  const float* W1 = (const float*)d_in[7];
  const float* b1 = (const float*)d_in[8];
  const float* W2 = (const float*)d_in[9];
  const float* b2 = (const float*)d_in[10];
  const float* eps = (const float*)d_in[11];
  const float* lng = (const float*)d_in[12];
  const float* lnb = (const float*)d_in[13];
  float* out = (float*)d_out;

  const int n_nodes = in_sizes[1];             // 204288
  const int nE = in_sizes[0] / 2;              // 407552
  const int n_species = in_sizes[6] / 64 - 1;  // 200
  const int n_edges = in_sizes[4] / n_species; // 397
  const int L = in_sizes[11];                  // 2
  const int n_gt = 512;                        // fixed problem size

  // Workspace layout:
  //   region0 [xb]: x  (later reused as gt_means [E,G,64])
  //   region1 [xb]: msg (later: pool sums | cnts | has | slist | scount)
  float* x = (float*)d_ws;
  size_t xb = (size_t)n_nodes * 64 * sizeof(float);
  float* msg = (float*)((char*)d_ws + xb);
  float* sums = msg;
  size_t poolb = (size_t)n_gt * n_species * 64 * sizeof(float);
  float* cnts = (float*)((char*)msg + poolb);
  size_t cntb = (size_t)n_gt * n_species * sizeof(float);
  float* has = (float*)((char*)cnts + cntb);
  size_t hasb = (size_t)n_edges * n_gt * sizeof(float);
  int* slist = (int*)((char*)has + hasb);
  int* scount = (int*)((char*)slist + (size_t)n_edges * SMAX * sizeof(int));
  float* gmat = x;  // x is dead after k_pool

  int embBlocks = (n_nodes * 16 + 255) / 256;
  k_embed<<<embBlocks, 256, 0, stream>>>(emb, sp_ids, x, n_nodes, n_species);

  for (int l = 0; l < L; ++l) {
    hipMemsetAsync(msg, 0, xb, stream);
    int scB = (nE * 16 + 255) / 256;
    k_scatter<<<scB, 256, 0, stream>>>(x, msg, edge_index, edge_index + nE, nE);
    int mlB = (n_nodes + 3) / 4;
    k_mlp<<<mlB, 256, 0, stream>>>(x, msg, W1 + l * 4096, b1 + l * 64,
                                   W2 + l * 4096, b2 + l * 64, eps + l,
                                   lng + l * 64, lnb + l * 64, x, n_nodes);
  }

  hipMemsetAsync(sums, 0, poolb + cntb, stream);
  k_pool<<<embBlocks, 256, 0, stream>>>(x, sp_ids, leaf_mask, batch_vec, sums,
                                        cnts, n_nodes, n_species);
  int pn = n_gt * n_species;
  k_norm<<<(pn * 16 + 255) / 256, 256, 0, stream>>>(sums, cnts, pn);
  k_slist<<<(n_edges + 3) / 4, 256, 0, stream>>>(clade_mask, slist, scount,
                                                 n_edges, n_species);
  k_gm<<<n_gt, 512, 0, stream>>>(sums, cnts, slist, scount, gmat, has,
                                 n_edges, n_species, n_gt);
  k_stat<<<n_edges, 512, 0, stream>>>(gmat, has, out, n_gt);
}

// Round 3
// 879.227 us; speedup vs baseline: 10.0131x; 2.2821x over previous
//
#include <hip/hip_runtime.h>

// D = 64 fixed throughout (16 float4 per row).
#define SMAX 200

__device__ __forceinline__ float rl(float v, int l) {
  return __int_as_float(__builtin_amdgcn_readlane(__float_as_int(v), l));
}
__device__ __forceinline__ float wredsum(float v) {
  for (int off = 32; off; off >>= 1) v += __shfl_xor(v, off);
  return v;
}

__global__ __launch_bounds__(256) void k_embed(const float* __restrict__ emb,
                                               const int* __restrict__ sp,
                                               float* __restrict__ x,
                                               int n_nodes, int n_species) {
  int t = blockIdx.x * 256 + threadIdx.x;
  int node = t >> 4, q = t & 15;
  if (node >= n_nodes) return;
  int s = sp[node];
  int row = (s < 0) ? n_species : s;
  reinterpret_cast<float4*>(x)[node * 16 + q] =
      reinterpret_cast<const float4*>(emb)[row * 16 + q];
}

// Second-half edges (parent->child) have UNIQUE destinations: plain stores.
// Tail of grid zeroes the root rows (no incoming parent edge).
__global__ __launch_bounds__(256) void k_msg_init(const float* __restrict__ x,
                                                  float* __restrict__ msg,
                                                  const int* __restrict__ srcH,
                                                  const int* __restrict__ dstH,
                                                  int E, int n_gt, int npg) {
  int t = blockIdx.x * 256 + threadIdx.x;
  int e = t >> 4, q = t & 15;
  if (e < E) {
    int s = srcH[e], d = dstH[e];
    reinterpret_cast<float4*>(msg)[d * 16 + q] =
        reinterpret_cast<const float4*>(x)[s * 16 + q];
  } else if (e < E + n_gt) {
    int g = e - E;
    float4 z = {0.f, 0.f, 0.f, 0.f};
    reinterpret_cast<float4*>(msg)[(size_t)g * npg * 16 + q] = z;
  }
}

// First-half edges (child->parent): parents repeat -> atomics.
__global__ __launch_bounds__(256) void k_scatter(const float* __restrict__ x,
                                                 float* __restrict__ msg,
                                                 const int* __restrict__ src,
                                                 const int* __restrict__ dst,
                                                 int E) {
  int t = blockIdx.x * 256 + threadIdx.x;
  int e = t >> 4, q = t & 15;
  if (e >= E) return;
  int s = src[e], d = dst[e];
  float4 v = reinterpret_cast<const float4*>(x)[s * 16 + q];
  float* m = msg + (size_t)d * 64 + q * 4;
  atomicAdd(m + 0, v.x);
  atomicAdd(m + 1, v.y);
  atomicAdd(m + 2, v.z);
  atomicAdd(m + 3, v.w);
}

// 16 nodes/block, 4 nodes/wave (lane = output dim). Broadcast of u[k]
// via v_readlane (VALU) -> 4 independent FMA chains; one conflict-free
// ds_read_b32 of the weight column shared by all 4 nodes.
__global__ __launch_bounds__(256) void k_mlp(const float* __restrict__ x_in,
                                             const float* __restrict__ msg,
                                             const float* __restrict__ W1,
                                             const float* __restrict__ b1,
                                             const float* __restrict__ W2,
                                             const float* __restrict__ b2,
                                             const float* __restrict__ eps_p,
                                             const float* __restrict__ gam,
                                             const float* __restrict__ bet,
                                             float* __restrict__ x_out, int n) {
  __shared__ __attribute__((aligned(16))) float sW1[64 * 64];
  __shared__ __attribute__((aligned(16))) float sW2[64 * 64];
  __shared__ float sb1[64], sb2[64], sg[64], sb[64];
  int tid = threadIdx.x;
  for (int i = tid; i < 1024; i += 256) {
    reinterpret_cast<float4*>(sW1)[i] = reinterpret_cast<const float4*>(W1)[i];
    reinterpret_cast<float4*>(sW2)[i] = reinterpret_cast<const float4*>(W2)[i];
  }
  if (tid < 64) {
    sb1[tid] = b1[tid];
    sb2[tid] = b2[tid];
    sg[tid] = gam[tid];
    sb[tid] = bet[tid];
  }
  __syncthreads();
  int w = tid >> 6, lane = tid & 63;
  int base = blockIdx.x * 16 + w * 4;
  if (base >= n) return;
  float e1 = 1.0f + eps_p[0];
  const float* xr = x_in + (size_t)base * 64 + lane;
  const float* mr = msg + (size_t)base * 64 + lane;
  float xv0 = xr[0], xv1 = xr[64], xv2 = xr[128], xv3 = xr[192];
  float u0 = fmaf(e1, xv0, mr[0]);
  float u1 = fmaf(e1, xv1, mr[64]);
  float u2 = fmaf(e1, xv2, mr[128]);
  float u3 = fmaf(e1, xv3, mr[192]);
  float t0 = sb1[lane], t1 = t0, t2 = t0, t3 = t0;
#pragma unroll
  for (int k = 0; k < 64; ++k) {
    float wk = sW1[k * 64 + lane];
    t0 = fmaf(rl(u0, k), wk, t0);
    t1 = fmaf(rl(u1, k), wk, t1);
    t2 = fmaf(rl(u2, k), wk, t2);
    t3 = fmaf(rl(u3, k), wk, t3);
  }
  t0 = fmaxf(t0, 0.f);
  t1 = fmaxf(t1, 0.f);
  t2 = fmaxf(t2, 0.f);
  t3 = fmaxf(t3, 0.f);
  float h0 = sb2[lane], h1 = h0, h2 = h0, h3 = h0;
#pragma unroll
  for (int k = 0; k < 64; ++k) {
    float wk = sW2[k * 64 + lane];
    h0 = fmaf(rl(t0, k), wk, h0);
    h1 = fmaf(rl(t1, k), wk, h1);
    h2 = fmaf(rl(t2, k), wk, h2);
    h3 = fmaf(rl(t3, k), wk, h3);
  }
  float g = sg[lane], bb = sb[lane];
  float* xo = x_out + (size_t)base * 64 + lane;
  {
    float y = xv0 + h0;
    float mu = wredsum(y) * (1.f / 64.f);
    float d0 = y - mu;
    float v = wredsum(d0 * d0) * (1.f / 64.f);
    xo[0] = d0 * rsqrtf(v + 1e-5f) * g + bb;
  }
  {
    float y = xv1 + h1;
    float mu = wredsum(y) * (1.f / 64.f);
    float d0 = y - mu;
    float v = wredsum(d0 * d0) * (1.f / 64.f);
    xo[64] = d0 * rsqrtf(v + 1e-5f) * g + bb;
  }
  {
    float y = xv2 + h2;
    float mu = wredsum(y) * (1.f / 64.f);
    float d0 = y - mu;
    float v = wredsum(d0 * d0) * (1.f / 64.f);
    xo[128] = d0 * rsqrtf(v + 1e-5f) * g + bb;
  }
  {
    float y = xv3 + h3;
    float mu = wredsum(y) * (1.f / 64.f);
    float d0 = y - mu;
    float v = wredsum(d0 * d0) * (1.f / 64.f);
    xo[192] = d0 * rsqrtf(v + 1e-5f) * g + bb;
  }
}

__global__ __launch_bounds__(256) void k_pool(const float* __restrict__ x,
                                              const int* __restrict__ sp,
                                              const int* __restrict__ leaf,
                                              const int* __restrict__ batch,
                                              float* __restrict__ sums,
                                              float* __restrict__ cnts,
                                              int n_nodes, int n_species) {
  int t = blockIdx.x * 256 + threadIdx.x;
  int node = t >> 4, q = t & 15;
  if (node >= n_nodes) return;
  int s = sp[node];
  if (s < 0 || !leaf[node]) return;
  int comp = batch[node] * n_species + s;
  float4 v = reinterpret_cast<const float4*>(x)[node * 16 + q];
  float* p = sums + (size_t)comp * 64 + q * 4;
  atomicAdd(p + 0, v.x);
  atomicAdd(p + 1, v.y);
  atomicAdd(p + 2, v.z);
  atomicAdd(p + 3, v.w);
  if (q == 0) atomicAdd(cnts + comp, 1.0f);
}

__global__ __launch_bounds__(256) void k_norm(float* __restrict__ sums,
                                              const float* __restrict__ cnts,
                                              int pool_n) {
  int t = blockIdx.x * 256 + threadIdx.x;
  int comp = t >> 4, q = t & 15;
  if (comp >= pool_n) return;
  float c = cnts[comp];
  float sc = 1.0f / fmaxf(c, 1.0f);
  float4 v = reinterpret_cast<float4*>(sums)[comp * 16 + q];
  v.x *= sc; v.y *= sc; v.z *= sc; v.w *= sc;
  reinterpret_cast<float4*>(sums)[comp * 16 + q] = v;
}

// Compact the clade mask into per-edge species lists via ballot/popcount.
__global__ __launch_bounds__(256) void k_slist(const int* __restrict__ clade,
                                               int* __restrict__ slist,
                                               int* __restrict__ scount,
                                               int n_edges, int n_species) {
  int wid = (blockIdx.x * 256 + threadIdx.x) >> 6;
  int lane = threadIdx.x & 63;
  if (wid >= n_edges) return;
  const int* row = clade + (size_t)wid * n_species;
  int base = 0;
  for (int b = 0; b < n_species; b += 64) {
    int idx = b + lane;
    bool pred = (idx < n_species) && (row[idx] != 0);
    unsigned long long m = __ballot(pred);
    int pos = __popcll(m & ((1ULL << lane) - 1ULL));
    if (pred) slist[(size_t)wid * SMAX + base + pos] = idx;
    base += __popcll(m);
  }
  if (lane == 0) scount[wid] = base;
}

// One block per gene tree. Wave handles 4 edges at once: lane = (edge-sub,
// float4-dim). Species id broadcast per-16-lane-group via ds_bpermute; pool
// row read as one ds_read_b128 (padded rows: 68 floats, bank-spread).
__global__ __launch_bounds__(512) void k_gm(const float* __restrict__ pool,
                                            const float* __restrict__ cnts,
                                            const int* __restrict__ slist,
                                            const int* __restrict__ scount,
                                            float* __restrict__ gm_out,
                                            float* __restrict__ has_out,
                                            int n_edges, int n_species,
                                            int n_gt) {
  __shared__ __attribute__((aligned(16))) float sPool[200 * 68];
  __shared__ float sValid[200];
  int g = blockIdx.x;
  int tid = threadIdx.x;
  const float* pg = pool + (size_t)g * n_species * 64;
  for (int i = tid; i < n_species * 64; i += 512)
    sPool[(i >> 6) * 68 + (i & 63)] = pg[i];
  for (int i = tid; i < n_species; i += 512)
    sValid[i] = (cnts[(size_t)g * n_species + i] > 0.f) ? 1.f : 0.f;
  __syncthreads();
  int w = tid >> 6, lane = tid & 63;
  int lq = lane & 15;
  int ngroups = (n_edges + 3) >> 2;
  for (int eg = w; eg < ngroups; eg += 8) {
    int e = eg * 4 + (lane >> 4);
    bool ev = e < n_edges;
    int nc = ev ? scount[e] : 0;
    int ncm = nc;
    ncm = max(ncm, __shfl_xor(ncm, 16));
    ncm = max(ncm, __shfl_xor(ncm, 32));
    const int* sl = slist + (size_t)(ev ? e : 0) * SMAX;
    float4 csum = {0.f, 0.f, 0.f, 0.f};
    float vc = 0.f;
    for (int c = 0; c < ncm; c += 16) {
      int j = c + lq;
      int r = (j < nc) ? sl[j] : 0;
      vc += (j < nc) ? sValid[r] : 0.f;
      int rem = nc - c;
      int lim = min(16, ncm - c);
      for (int i = 0; i < lim; ++i) {
        int s = __builtin_amdgcn_ds_bpermute(((lane & 48) | i) << 2, r);
        const float4 v =
            *reinterpret_cast<const float4*>(&sPool[s * 68 + lq * 4]);
        if (i < rem) {
          csum.x += v.x;
          csum.y += v.y;
          csum.z += v.z;
          csum.w += v.w;
        }
      }
    }
    vc += __shfl_xor(vc, 1);
    vc += __shfl_xor(vc, 2);
    vc += __shfl_xor(vc, 4);
    vc += __shfl_xor(vc, 8);
    if (ev) {
      float inv = 1.f / fmaxf(vc, 1.f);
      float4 gm = {csum.x * inv, csum.y * inv, csum.z * inv, csum.w * inv};
      *reinterpret_cast<float4*>(&gm_out[((size_t)e * n_gt + g) * 64 + lq * 4]) =
          gm;
      if (lq == 0) has_out[(size_t)e * n_gt + g] = (vc > 0.f) ? 1.f : 0.f;
    }
  }
}

// One block per species-tree edge: streaming mean/std over gene trees.
__global__ __launch_bounds__(512) void k_stat(const float* __restrict__ gmat,
                                              const float* __restrict__ has,
                                              float* __restrict__ out,
                                              int n_gt) {
  __shared__ float red1[8][64];
  __shared__ float red2[8][64];
  __shared__ float redn[8];
  int e = blockIdx.x;
  int tid = threadIdx.x, w = tid >> 6, lane = tid & 63;
  const float* ge = gmat + (size_t)e * n_gt * 64;
  const float* he = has + (size_t)e * n_gt;
  float S1 = 0.f, S2 = 0.f, nv = 0.f;
  for (int g = w; g < n_gt; g += 8) {
    float h = he[g];
    float v = ge[g * 64 + lane];
    S1 += h * v;
    S2 += h * v * v;
    nv += h;
  }
  red1[w][lane] = S1;
  red2[w][lane] = S2;
  if (lane == 0) redn[w] = nv;
  __syncthreads();
  if (w == 0) {
    float s1 = 0.f, s2 = 0.f, n_v = 0.f;
#pragma unroll
    for (int j = 0; j < 8; ++j) {
      s1 += red1[j][lane];
      s2 += red2[j][lane];
      n_v += redn[j];
    }
    float mean = s1 / fmaxf(n_v, 1.f);
    float var = (s2 - s1 * s1 / fmaxf(n_v, 1.f)) / fmaxf(n_v - 1.f, 1.f);
    float stdv = (n_v > 1.f) ? sqrtf(fmaxf(var, 0.f)) : 0.f;
    out[(size_t)e * 128 + lane] = (n_v > 0.f) ? mean : 0.f;
    out[(size_t)e * 128 + 64 + lane] = stdv;
  }
}

extern "C" void kernel_launch(void* const* d_in, const int* in_sizes, int n_in,
                              void* d_out, int out_size, void* d_ws, size_t ws_size,
                              hipStream_t stream) {
  (void)n_in; (void)out_size; (void)ws_size;
  const int* edge_index = (const int*)d_in[0];
  const int* sp_ids = (const int*)d_in[1];
  const int* leaf_mask = (const int*)d_in[2];
  const int* batch_vec = (const int*)d_in[3];
  const int* clade_mask = (const int*)d_in[4];
  // d_in[5] = n_gt scalar (device); shapes are fixed for this problem.
  const float* emb = (const float*)d_in[6];
  const float* W1 = (const float*)d_in[7];
  const float* b1 = (const float*)d_in[8];
  const float* W2 = (const float*)d_in[9];
  const float* b2 = (const float*)d_in[10];
  const float* eps = (const float*)d_in[11];
  const float* lng = (const float*)d_in[12];
  const float* lnb = (const float*)d_in[13];
  float* out = (float*)d_out;

  const int n_nodes = in_sizes[1];             // 204288
  const int nE = in_sizes[0] / 2;              // 407552 directed edges
  const int E = nE / 2;                        // 203776 per direction-half
  const int n_species = in_sizes[6] / 64 - 1;  // 200
  const int n_edges = in_sizes[4] / n_species; // 397
  const int L = in_sizes[11];                  // 2
  const int n_gt = 512;                        // fixed problem size
  const int npg = n_nodes / n_gt;              // 399 nodes per gene tree

  const int* src = edge_index;       // directed src, length nE
  const int* dst = edge_index + nE;  // directed dst, length nE

  float* x = (float*)d_ws;
  size_t xb = (size_t)n_nodes * 64 * sizeof(float);
  float* msg = (float*)((char*)d_ws + xb);
  float* sums = msg;
  size_t poolb = (size_t)n_gt * n_species * 64 * sizeof(float);
  float* cnts = (float*)((char*)msg + poolb);
  size_t cntb = (size_t)n_gt * n_species * sizeof(float);
  float* has = (float*)((char*)cnts + cntb);
  size_t hasb = (size_t)n_edges * n_gt * sizeof(float);
  int* slist = (int*)((char*)has + hasb);
  int* scount = (int*)((char*)slist + (size_t)n_edges * SMAX * sizeof(int));
  float* gmat = x;  // x is dead after k_pool

  int embBlocks = (n_nodes * 16 + 255) / 256;
  k_embed<<<embBlocks, 256, 0, stream>>>(emb, sp_ids, x, n_nodes, n_species);

  int initB = ((E + n_gt) * 16 + 255) / 256;
  int scB = (E * 16 + 255) / 256;
  int mlB = (n_nodes + 15) / 16;
  for (int l = 0; l < L; ++l) {
    k_msg_init<<<initB, 256, 0, stream>>>(x, msg, src + E, dst + E, E, n_gt,
                                          npg);
    k_scatter<<<scB, 256, 0, stream>>>(x, msg, src, dst, E);
    k_mlp<<<mlB, 256, 0, stream>>>(x, msg, W1 + l * 4096, b1 + l * 64,
                                   W2 + l * 4096, b2 + l * 64, eps + l,
                                   lng + l * 64, lnb + l * 64, x, n_nodes);
  }

  hipMemsetAsync(sums, 0, poolb + cntb, stream);
  k_pool<<<embBlocks, 256, 0, stream>>>(x, sp_ids, leaf_mask, batch_vec, sums,
                                        cnts, n_nodes, n_species);
  int pn = n_gt * n_species;
  k_norm<<<(pn * 16 + 255) / 256, 256, 0, stream>>>(sums, cnts, pn);
  k_slist<<<(n_edges + 3) / 4, 256, 0, stream>>>(clade_mask, slist, scount,
                                                 n_edges, n_species);
  k_gm<<<n_gt, 512, 0, stream>>>(sums, cnts, slist, scount, gmat, has,
                                 n_edges, n_species, n_gt);
  k_stat<<<n_edges, 512, 0, stream>>>(gmat, has, out, n_gt);
}

// Round 4
// 811.945 us; speedup vs baseline: 10.8429x; 1.0829x over previous
//
#include <hip/hip_runtime.h>

// D = 64 fixed throughout (16 float4 per row).
#define SMAX 200

__device__ __forceinline__ float rl(float v, int l) {
  return __int_as_float(__builtin_amdgcn_readlane(__float_as_int(v), l));
}
__device__ __forceinline__ float wredsum(float v) {
  for (int off = 32; off; off >>= 1) v += __shfl_xor(v, off);
  return v;
}

__global__ __launch_bounds__(256) void k_embed(const float* __restrict__ emb,
                                               const int* __restrict__ sp,
                                               float* __restrict__ x,
                                               int n_nodes, int n_species) {
  int t = blockIdx.x * 256 + threadIdx.x;
  int node = t >> 4, q = t & 15;
  if (node >= n_nodes) return;
  int s = sp[node];
  int row = (s < 0) ? n_species : s;
  reinterpret_cast<float4*>(x)[node * 16 + q] =
      reinterpret_cast<const float4*>(emb)[row * 16 + q];
}

// Message pass without global atomics: 2 blocks per gene tree, each owning a
// 200-node slice. First-half edges (src=child, dst=parent) carry both
// directions: x[c] -> acc[p] (child sums) and x[p] -> acc[c] (parent msg).
// LDS atomics only; contiguous float4 dump at the end.
__global__ __launch_bounds__(512) void k_msg(const float* __restrict__ x,
                                             float* __restrict__ msg,
                                             const int* __restrict__ src,
                                             const int* __restrict__ dst,
                                             int npg) {
  __shared__ __attribute__((aligned(16))) float acc[200 * 64];
  __shared__ int sC[400], sP[400];
  int b = blockIdx.x;
  int g = b >> 1, half = b & 1;
  int lo = half ? 200 : 0;
  int hi = half ? npg : 200;
  int nloc = hi - lo;
  int nE = npg - 1;  // 398 edges per tree
  int tid = threadIdx.x;
  for (int i = tid; i < nloc * 64; i += 512) acc[i] = 0.f;
  int ebase = g * nE;
  for (int i = tid; i < nE; i += 512) {
    sC[i] = src[ebase + i] - g * npg;
    sP[i] = dst[ebase + i] - g * npg;
  }
  __syncthreads();
  int w = tid >> 6, lane = tid & 63;
  const float* xg = x + (size_t)g * npg * 64;
  for (int i = w; i < nE; i += 8) {
    int cl = sC[i], pl = sP[i];
    if (pl >= lo && pl < hi)
      atomicAdd(&acc[(pl - lo) * 64 + lane], xg[cl * 64 + lane]);
    if (cl >= lo && cl < hi)
      atomicAdd(&acc[(cl - lo) * 64 + lane], xg[pl * 64 + lane]);
  }
  __syncthreads();
  float* mg = msg + (size_t)g * npg * 64 + (size_t)lo * 64;
  for (int i = tid; i < nloc * 16; i += 512)
    reinterpret_cast<float4*>(mg)[i] = reinterpret_cast<const float4*>(acc)[i];
}

// 16 nodes/block, 4 nodes/wave (lane = output dim). Broadcast of u[k]
// via v_readlane (VALU) -> 4 independent FMA chains; one conflict-free
// ds_read_b32 of the weight column shared by all 4 nodes.
__global__ __launch_bounds__(256) void k_mlp(const float* __restrict__ x_in,
                                             const float* __restrict__ msg,
                                             const float* __restrict__ W1,
                                             const float* __restrict__ b1,
                                             const float* __restrict__ W2,
                                             const float* __restrict__ b2,
                                             const float* __restrict__ eps_p,
                                             const float* __restrict__ gam,
                                             const float* __restrict__ bet,
                                             float* __restrict__ x_out, int n) {
  __shared__ __attribute__((aligned(16))) float sW1[64 * 64];
  __shared__ __attribute__((aligned(16))) float sW2[64 * 64];
  __shared__ float sb1[64], sb2[64], sg[64], sb[64];
  int tid = threadIdx.x;
  for (int i = tid; i < 1024; i += 256) {
    reinterpret_cast<float4*>(sW1)[i] = reinterpret_cast<const float4*>(W1)[i];
    reinterpret_cast<float4*>(sW2)[i] = reinterpret_cast<const float4*>(W2)[i];
  }
  if (tid < 64) {
    sb1[tid] = b1[tid];
    sb2[tid] = b2[tid];
    sg[tid] = gam[tid];
    sb[tid] = bet[tid];
  }
  __syncthreads();
  int w = tid >> 6, lane = tid & 63;
  int base = blockIdx.x * 16 + w * 4;
  if (base >= n) return;
  float e1 = 1.0f + eps_p[0];
  const float* xr = x_in + (size_t)base * 64 + lane;
  const float* mr = msg + (size_t)base * 64 + lane;
  float xv0 = xr[0], xv1 = xr[64], xv2 = xr[128], xv3 = xr[192];
  float u0 = fmaf(e1, xv0, mr[0]);
  float u1 = fmaf(e1, xv1, mr[64]);
  float u2 = fmaf(e1, xv2, mr[128]);
  float u3 = fmaf(e1, xv3, mr[192]);
  float t0 = sb1[lane], t1 = t0, t2 = t0, t3 = t0;
#pragma unroll
  for (int k = 0; k < 64; ++k) {
    float wk = sW1[k * 64 + lane];
    t0 = fmaf(rl(u0, k), wk, t0);
    t1 = fmaf(rl(u1, k), wk, t1);
    t2 = fmaf(rl(u2, k), wk, t2);
    t3 = fmaf(rl(u3, k), wk, t3);
  }
  t0 = fmaxf(t0, 0.f);
  t1 = fmaxf(t1, 0.f);
  t2 = fmaxf(t2, 0.f);
  t3 = fmaxf(t3, 0.f);
  float h0 = sb2[lane], h1 = h0, h2 = h0, h3 = h0;
#pragma unroll
  for (int k = 0; k < 64; ++k) {
    float wk = sW2[k * 64 + lane];
    h0 = fmaf(rl(t0, k), wk, h0);
    h1 = fmaf(rl(t1, k), wk, h1);
    h2 = fmaf(rl(t2, k), wk, h2);
    h3 = fmaf(rl(t3, k), wk, h3);
  }
  float g = sg[lane], bb = sb[lane];
  float* xo = x_out + (size_t)base * 64 + lane;
  {
    float y = xv0 + h0;
    float mu = wredsum(y) * (1.f / 64.f);
    float d0 = y - mu;
    float v = wredsum(d0 * d0) * (1.f / 64.f);
    xo[0] = d0 * rsqrtf(v + 1e-5f) * g + bb;
  }
  {
    float y = xv1 + h1;
    float mu = wredsum(y) * (1.f / 64.f);
    float d0 = y - mu;
    float v = wredsum(d0 * d0) * (1.f / 64.f);
    xo[64] = d0 * rsqrtf(v + 1e-5f) * g + bb;
  }
  {
    float y = xv2 + h2;
    float mu = wredsum(y) * (1.f / 64.f);
    float d0 = y - mu;
    float v = wredsum(d0 * d0) * (1.f / 64.f);
    xo[128] = d0 * rsqrtf(v + 1e-5f) * g + bb;
  }
  {
    float y = xv3 + h3;
    float mu = wredsum(y) * (1.f / 64.f);
    float d0 = y - mu;
    float v = wredsum(d0 * d0) * (1.f / 64.f);
    xo[192] = d0 * rsqrtf(v + 1e-5f) * g + bb;
  }
}

// Species pooling, no global atomics: block per gene tree, LDS accumulation
// (comp = g*S+s is owned entirely by tree g), fused mean + valid-flag write.
__global__ __launch_bounds__(256) void k_pool(const float* __restrict__ x,
                                              const int* __restrict__ sp,
                                              const int* __restrict__ leaf,
                                              float* __restrict__ pool,
                                              float* __restrict__ vcnt,
                                              int npg, int n_species) {
  __shared__ __attribute__((aligned(16))) float acc[200 * 64];
  __shared__ float cnt[200];
  int g = blockIdx.x;
  int tid = threadIdx.x;
  for (int i = tid; i < n_species * 64; i += 256) acc[i] = 0.f;
  for (int i = tid; i < n_species; i += 256) cnt[i] = 0.f;
  __syncthreads();
  int w = tid >> 6, lane = tid & 63;
  for (int i = w; i < npg; i += 4) {
    int node = g * npg + i;
    int s = sp[node];
    if (s >= 0 && leaf[node]) {
      atomicAdd(&acc[s * 64 + lane], x[(size_t)node * 64 + lane]);
      if (lane == 0) atomicAdd(&cnt[s], 1.f);
    }
  }
  __syncthreads();
  float* pg = pool + (size_t)g * n_species * 64;
  for (int i = tid; i < n_species * 64; i += 256)
    pg[i] = acc[i] / fmaxf(cnt[i >> 6], 1.f);
  for (int i = tid; i < n_species; i += 256)
    vcnt[(size_t)g * n_species + i] = (cnt[i] > 0.f) ? 1.f : 0.f;
}

// Compact the clade mask into per-edge species lists via ballot/popcount.
__global__ __launch_bounds__(256) void k_slist(const int* __restrict__ clade,
                                               int* __restrict__ slist,
                                               int* __restrict__ scount,
                                               int n_edges, int n_species) {
  int wid = (blockIdx.x * 256 + threadIdx.x) >> 6;
  int lane = threadIdx.x & 63;
  if (wid >= n_edges) return;
  const int* row = clade + (size_t)wid * n_species;
  int base = 0;
  for (int b = 0; b < n_species; b += 64) {
    int idx = b + lane;
    bool pred = (idx < n_species) && (row[idx] != 0);
    unsigned long long m = __ballot(pred);
    int pos = __popcll(m & ((1ULL << lane) - 1ULL));
    if (pred) slist[(size_t)wid * SMAX + base + pos] = idx;
    base += __popcll(m);
  }
  if (lane == 0) scount[wid] = base;
}

// One block per gene tree. Wave handles 4 edges at once: lane = (edge-sub,
// float4-dim). Species id broadcast per-16-lane-group via ds_bpermute; pool
// row read as one ds_read_b128 (padded rows: 68 floats, bank-spread).
__global__ __launch_bounds__(512) void k_gm(const float* __restrict__ pool,
                                            const float* __restrict__ vcnt,
                                            const int* __restrict__ slist,
                                            const int* __restrict__ scount,
                                            float* __restrict__ gm_out,
                                            float* __restrict__ has_out,
                                            int n_edges, int n_species,
                                            int n_gt) {
  __shared__ __attribute__((aligned(16))) float sPool[200 * 68];
  __shared__ float sValid[200];
  int g = blockIdx.x;
  int tid = threadIdx.x;
  const float* pg = pool + (size_t)g * n_species * 64;
  for (int i = tid; i < n_species * 64; i += 512)
    sPool[(i >> 6) * 68 + (i & 63)] = pg[i];
  for (int i = tid; i < n_species; i += 512)
    sValid[i] = vcnt[(size_t)g * n_species + i];
  __syncthreads();
  int w = tid >> 6, lane = tid & 63;
  int lq = lane & 15;
  int ngroups = (n_edges + 3) >> 2;
  for (int eg = w; eg < ngroups; eg += 8) {
    int e = eg * 4 + (lane >> 4);
    bool ev = e < n_edges;
    int nc = ev ? scount[e] : 0;
    int ncm = nc;
    ncm = max(ncm, __shfl_xor(ncm, 16));
    ncm = max(ncm, __shfl_xor(ncm, 32));
    const int* sl = slist + (size_t)(ev ? e : 0) * SMAX;
    float4 csum = {0.f, 0.f, 0.f, 0.f};
    float vc = 0.f;
    for (int c = 0; c < ncm; c += 16) {
      int j = c + lq;
      int r = (j < nc) ? sl[j] : 0;
      vc += (j < nc) ? sValid[r] : 0.f;
      int rem = nc - c;
      int lim = min(16, ncm - c);
      for (int i = 0; i < lim; ++i) {
        int s = __builtin_amdgcn_ds_bpermute(((lane & 48) | i) << 2, r);
        const float4 v =
            *reinterpret_cast<const float4*>(&sPool[s * 68 + lq * 4]);
        if (i < rem) {
          csum.x += v.x;
          csum.y += v.y;
          csum.z += v.z;
          csum.w += v.w;
        }
      }
    }
    vc += __shfl_xor(vc, 1);
    vc += __shfl_xor(vc, 2);
    vc += __shfl_xor(vc, 4);
    vc += __shfl_xor(vc, 8);
    if (ev) {
      float inv = 1.f / fmaxf(vc, 1.f);
      float4 gm = {csum.x * inv, csum.y * inv, csum.z * inv, csum.w * inv};
      *reinterpret_cast<float4*>(&gm_out[((size_t)e * n_gt + g) * 64 + lq * 4]) =
          gm;
      if (lq == 0) has_out[(size_t)e * n_gt + g] = (vc > 0.f) ? 1.f : 0.f;
    }
  }
}

// One block per species-tree edge: streaming mean/std over gene trees.
__global__ __launch_bounds__(512) void k_stat(const float* __restrict__ gmat,
                                              const float* __restrict__ has,
                                              float* __restrict__ out,
                                              int n_gt) {
  __shared__ float red1[8][64];
  __shared__ float red2[8][64];
  __shared__ float redn[8];
  int e = blockIdx.x;
  int tid = threadIdx.x, w = tid >> 6, lane = tid & 63;
  const float* ge = gmat + (size_t)e * n_gt * 64;
  const float* he = has + (size_t)e * n_gt;
  float S1 = 0.f, S2 = 0.f, nv = 0.f;
  for (int g = w; g < n_gt; g += 8) {
    float h = he[g];
    float v = ge[g * 64 + lane];
    S1 += h * v;
    S2 += h * v * v;
    nv += h;
  }
  red1[w][lane] = S1;
  red2[w][lane] = S2;
  if (lane == 0) redn[w] = nv;
  __syncthreads();
  if (w == 0) {
    float s1 = 0.f, s2 = 0.f, n_v = 0.f;
#pragma unroll
    for (int j = 0; j < 8; ++j) {
      s1 += red1[j][lane];
      s2 += red2[j][lane];
      n_v += redn[j];
    }
    float mean = s1 / fmaxf(n_v, 1.f);
    float var = (s2 - s1 * s1 / fmaxf(n_v, 1.f)) / fmaxf(n_v - 1.f, 1.f);
    float stdv = (n_v > 1.f) ? sqrtf(fmaxf(var, 0.f)) : 0.f;
    out[(size_t)e * 128 + lane] = (n_v > 0.f) ? mean : 0.f;
    out[(size_t)e * 128 + 64 + lane] = stdv;
  }
}

extern "C" void kernel_launch(void* const* d_in, const int* in_sizes, int n_in,
                              void* d_out, int out_size, void* d_ws, size_t ws_size,
                              hipStream_t stream) {
  (void)n_in; (void)out_size; (void)ws_size;
  const int* edge_index = (const int*)d_in[0];
  const int* sp_ids = (const int*)d_in[1];
  const int* leaf_mask = (const int*)d_in[2];
  const int* clade_mask = (const int*)d_in[4];
  const float* emb = (const float*)d_in[6];
  const float* W1 = (const float*)d_in[7];
  const float* b1 = (const float*)d_in[8];
  const float* W2 = (const float*)d_in[9];
  const float* b2 = (const float*)d_in[10];
  const float* eps = (const float*)d_in[11];
  const float* lng = (const float*)d_in[12];
  const float* lnb = (const float*)d_in[13];
  float* out = (float*)d_out;

  const int n_nodes = in_sizes[1];             // 204288
  const int nE = in_sizes[0] / 2;              // 407552 directed edges
  const int E = nE / 2;                        // 203776 per direction-half
  const int n_species = in_sizes[6] / 64 - 1;  // 200
  const int n_edges = in_sizes[4] / n_species; // 397
  const int L = in_sizes[11];                  // 2
  const int n_gt = 512;                        // fixed problem size
  const int npg = n_nodes / n_gt;              // 399 nodes per gene tree

  const int* src = edge_index;       // directed src, length nE (first half: child)
  const int* dst = edge_index + nE;  // directed dst, length nE (first half: parent)
  (void)E;

  float* x = (float*)d_ws;
  size_t xb = (size_t)n_nodes * 64 * sizeof(float);
  float* msg = (float*)((char*)d_ws + xb);
  float* pool = msg;  // msg region reused after GNN layers
  size_t poolb = (size_t)n_gt * n_species * 64 * sizeof(float);
  float* vcnt = (float*)((char*)pool + poolb);
  size_t cntb = (size_t)n_gt * n_species * sizeof(float);
  float* has = (float*)((char*)vcnt + cntb);
  size_t hasb = (size_t)n_edges * n_gt * sizeof(float);
  int* slist = (int*)((char*)has + hasb);
  int* scount = (int*)((char*)slist + (size_t)n_edges * SMAX * sizeof(int));
  float* gmat = x;  // x is dead after k_pool

  int embBlocks = (n_nodes * 16 + 255) / 256;
  k_embed<<<embBlocks, 256, 0, stream>>>(emb, sp_ids, x, n_nodes, n_species);

  int mlB = (n_nodes + 15) / 16;
  for (int l = 0; l < L; ++l) {
    k_msg<<<n_gt * 2, 512, 0, stream>>>(x, msg, src, dst, npg);
    k_mlp<<<mlB, 256, 0, stream>>>(x, msg, W1 + l * 4096, b1 + l * 64,
                                   W2 + l * 4096, b2 + l * 64, eps + l,
                                   lng + l * 64, lnb + l * 64, x, n_nodes);
  }

  k_pool<<<n_gt, 256, 0, stream>>>(x, sp_ids, leaf_mask, pool, vcnt, npg,
                                   n_species);
  k_slist<<<(n_edges + 3) / 4, 256, 0, stream>>>(clade_mask, slist, scount,
                                                 n_edges, n_species);
  k_gm<<<n_gt, 512, 0, stream>>>(pool, vcnt, slist, scount, gmat, has,
                                 n_edges, n_species, n_gt);
  k_stat<<<n_edges, 512, 0, stream>>>(gmat, has, out, n_gt);
}

// Round 5
// 518.376 us; speedup vs baseline: 16.9834x; 1.5663x over previous
//
#include <hip/hip_runtime.h>

// Fixed problem geometry: D=64, n_gt=512, npg=399 nodes/tree, 398 edges/tree.
#define SMAX 200
#define NPG 399

__device__ __forceinline__ float rl(float v, int l) {
  return __int_as_float(__builtin_amdgcn_readlane(__float_as_int(v), l));
}
__device__ __forceinline__ float wredsum(float v) {
  for (int off = 32; off; off >>= 1) v += __shfl_xor(v, off);
  return v;
}

__global__ __launch_bounds__(256) void k_embed(const float* __restrict__ emb,
                                               const int* __restrict__ sp,
                                               float* __restrict__ x,
                                               int n_nodes, int n_species) {
  int t = blockIdx.x * 256 + threadIdx.x;
  int node = t >> 4, q = t & 15;
  if (node >= n_nodes) return;
  int s = sp[node];
  int row = (s < 0) ? n_species : s;
  reinterpret_cast<float4*>(x)[node * 16 + q] =
      reinterpret_cast<const float4*>(emb)[row * 16 + q];
}

// One block per gene tree. Stage x[tree] (102 KB) in LDS, build the child-CSR
// in LDS (histogram -> Hillis-Steele scan -> scatter), then each wave computes
// msg[i] = sum_children x[c] + x[par[i]] from LDS. No atomics on global, no
// global gathers; child loop is wave-uniform (lane = feature dim).
__global__ __launch_bounds__(512) void k_msg(const float* __restrict__ x,
                                             float* __restrict__ msg,
                                             const int* __restrict__ src,
                                             const int* __restrict__ dst,
                                             int npg) {
  __shared__ __attribute__((aligned(16))) float sX[NPG * 64];
  __shared__ int sStart[NPG + 1];
  __shared__ int sChild[NPG - 1];
  __shared__ int sPar[NPG];
  __shared__ int sCnt[NPG];
  int g = blockIdx.x;
  int tid = threadIdx.x;
  int nEt = npg - 1;
  int base = g * npg;
  int ebase = g * nEt;
  // phase 0: zero counters
  for (int i = tid; i < npg + 1; i += 512) sStart[i] = 0;
  for (int i = tid; i < npg; i += 512) sCnt[i] = 0;
  __syncthreads();
  // phase 1: stage x, load edges, histogram child-counts per parent
  const float4* xg4 = reinterpret_cast<const float4*>(x + (size_t)base * 64);
  for (int i = tid; i < npg * 16; i += 512)
    reinterpret_cast<float4*>(sX)[i] = xg4[i];
  for (int i = tid; i < nEt; i += 512) {
    int c = src[ebase + i] - base;
    int p = dst[ebase + i] - base;
    sPar[c] = p;
    atomicAdd(&sStart[p + 1], 1);
  }
  __syncthreads();
  // phase 2: inclusive scan of sStart[0..npg] -> child-region starts
  for (int off = 1; off < npg + 1; off <<= 1) {
    int t = 0;
    if (tid < npg + 1 && tid >= off) t = sStart[tid - off];
    __syncthreads();
    if (tid < npg + 1 && tid >= off) sStart[tid] += t;
    __syncthreads();
  }
  // phase 3: scatter children (every non-root node is exactly one edge's child)
  for (int c = tid + 1; c < npg; c += 512) {
    int p = sPar[c];
    int pos = sStart[p] + atomicAdd(&sCnt[p], 1);
    sChild[pos] = c;
  }
  __syncthreads();
  // phase 4: per-wave node loop, all reads from LDS, coalesced global write
  int w = tid >> 6, lane = tid & 63;
  for (int i = w; i < npg; i += 8) {
    float s = 0.f;
    int j0 = sStart[i], j1 = sStart[i + 1];
    for (int j = j0; j < j1; ++j) s += sX[sChild[j] * 64 + lane];
    if (i > 0) s += sX[sPar[i] * 64 + lane];
    msg[(size_t)(base + i) * 64 + lane] = s;
  }
}

// 16 nodes/block, 4 nodes/wave (lane = output dim). Broadcast of u[k]
// via v_readlane (VALU) -> 4 independent FMA chains; one conflict-free
// ds_read_b32 of the weight column shared by all 4 nodes.
__global__ __launch_bounds__(256) void k_mlp(const float* __restrict__ x_in,
                                             const float* __restrict__ msg,
                                             const float* __restrict__ W1,
                                             const float* __restrict__ b1,
                                             const float* __restrict__ W2,
                                             const float* __restrict__ b2,
                                             const float* __restrict__ eps_p,
                                             const float* __restrict__ gam,
                                             const float* __restrict__ bet,
                                             float* __restrict__ x_out, int n) {
  __shared__ __attribute__((aligned(16))) float sW1[64 * 64];
  __shared__ __attribute__((aligned(16))) float sW2[64 * 64];
  __shared__ float sb1[64], sb2[64], sg[64], sb[64];
  int tid = threadIdx.x;
  for (int i = tid; i < 1024; i += 256) {
    reinterpret_cast<float4*>(sW1)[i] = reinterpret_cast<const float4*>(W1)[i];
    reinterpret_cast<float4*>(sW2)[i] = reinterpret_cast<const float4*>(W2)[i];
  }
  if (tid < 64) {
    sb1[tid] = b1[tid];
    sb2[tid] = b2[tid];
    sg[tid] = gam[tid];
    sb[tid] = bet[tid];
  }
  __syncthreads();
  int w = tid >> 6, lane = tid & 63;
  int base = blockIdx.x * 16 + w * 4;
  if (base >= n) return;
  float e1 = 1.0f + eps_p[0];
  const float* xr = x_in + (size_t)base * 64 + lane;
  const float* mr = msg + (size_t)base * 64 + lane;
  float xv0 = xr[0], xv1 = xr[64], xv2 = xr[128], xv3 = xr[192];
  float u0 = fmaf(e1, xv0, mr[0]);
  float u1 = fmaf(e1, xv1, mr[64]);
  float u2 = fmaf(e1, xv2, mr[128]);
  float u3 = fmaf(e1, xv3, mr[192]);
  float t0 = sb1[lane], t1 = t0, t2 = t0, t3 = t0;
#pragma unroll
  for (int k = 0; k < 64; ++k) {
    float wk = sW1[k * 64 + lane];
    t0 = fmaf(rl(u0, k), wk, t0);
    t1 = fmaf(rl(u1, k), wk, t1);
    t2 = fmaf(rl(u2, k), wk, t2);
    t3 = fmaf(rl(u3, k), wk, t3);
  }
  t0 = fmaxf(t0, 0.f);
  t1 = fmaxf(t1, 0.f);
  t2 = fmaxf(t2, 0.f);
  t3 = fmaxf(t3, 0.f);
  float h0 = sb2[lane], h1 = h0, h2 = h0, h3 = h0;
#pragma unroll
  for (int k = 0; k < 64; ++k) {
    float wk = sW2[k * 64 + lane];
    h0 = fmaf(rl(t0, k), wk, h0);
    h1 = fmaf(rl(t1, k), wk, h1);
    h2 = fmaf(rl(t2, k), wk, h2);
    h3 = fmaf(rl(t3, k), wk, h3);
  }
  float g = sg[lane], bb = sb[lane];
  float* xo = x_out + (size_t)base * 64 + lane;
  {
    float y = xv0 + h0;
    float mu = wredsum(y) * (1.f / 64.f);
    float d0 = y - mu;
    float v = wredsum(d0 * d0) * (1.f / 64.f);
    xo[0] = d0 * rsqrtf(v + 1e-5f) * g + bb;
  }
  {
    float y = xv1 + h1;
    float mu = wredsum(y) * (1.f / 64.f);
    float d0 = y - mu;
    float v = wredsum(d0 * d0) * (1.f / 64.f);
    xo[64] = d0 * rsqrtf(v + 1e-5f) * g + bb;
  }
  {
    float y = xv2 + h2;
    float mu = wredsum(y) * (1.f / 64.f);
    float d0 = y - mu;
    float v = wredsum(d0 * d0) * (1.f / 64.f);
    xo[128] = d0 * rsqrtf(v + 1e-5f) * g + bb;
  }
  {
    float y = xv3 + h3;
    float mu = wredsum(y) * (1.f / 64.f);
    float d0 = y - mu;
    float v = wredsum(d0 * d0) * (1.f / 64.f);
    xo[192] = d0 * rsqrtf(v + 1e-5f) * g + bb;
  }
}

// Species pooling, no global atomics: block per gene tree, LDS accumulation
// (comp = g*S+s is owned entirely by tree g), fused mean + valid-flag write.
__global__ __launch_bounds__(256) void k_pool(const float* __restrict__ x,
                                              const int* __restrict__ sp,
                                              const int* __restrict__ leaf,
                                              float* __restrict__ pool,
                                              float* __restrict__ vcnt,
                                              int npg, int n_species) {
  __shared__ __attribute__((aligned(16))) float acc[200 * 64];
  __shared__ float cnt[200];
  int g = blockIdx.x;
  int tid = threadIdx.x;
  for (int i = tid; i < n_species * 64; i += 256) acc[i] = 0.f;
  for (int i = tid; i < n_species; i += 256) cnt[i] = 0.f;
  __syncthreads();
  int w = tid >> 6, lane = tid & 63;
  for (int i = w; i < npg; i += 4) {
    int node = g * npg + i;
    int s = sp[node];
    if (s >= 0 && leaf[node]) {
      atomicAdd(&acc[s * 64 + lane], x[(size_t)node * 64 + lane]);
      if (lane == 0) atomicAdd(&cnt[s], 1.f);
    }
  }
  __syncthreads();
  float* pg = pool + (size_t)g * n_species * 64;
  for (int i = tid; i < n_species * 64; i += 256)
    pg[i] = acc[i] / fmaxf(cnt[i >> 6], 1.f);
  for (int i = tid; i < n_species; i += 256)
    vcnt[(size_t)g * n_species + i] = (cnt[i] > 0.f) ? 1.f : 0.f;
}

// Compact the clade mask into per-edge species lists via ballot/popcount.
__global__ __launch_bounds__(256) void k_slist(const int* __restrict__ clade,
                                               int* __restrict__ slist,
                                               int* __restrict__ scount,
                                               int n_edges, int n_species) {
  int wid = (blockIdx.x * 256 + threadIdx.x) >> 6;
  int lane = threadIdx.x & 63;
  if (wid >= n_edges) return;
  const int* row = clade + (size_t)wid * n_species;
  int base = 0;
  for (int b = 0; b < n_species; b += 64) {
    int idx = b + lane;
    bool pred = (idx < n_species) && (row[idx] != 0);
    unsigned long long m = __ballot(pred);
    int pos = __popcll(m & ((1ULL << lane) - 1ULL));
    if (pred) slist[(size_t)wid * SMAX + base + pos] = idx;
    base += __popcll(m);
  }
  if (lane == 0) scount[wid] = base;
}

// One block per gene tree. Wave handles 4 edges at once: lane = (edge-sub,
// float4-dim). Species id broadcast per-16-lane-group via ds_bpermute; pool
// row read as one ds_read_b128 (padded rows: 68 floats, bank-spread).
__global__ __launch_bounds__(512) void k_gm(const float* __restrict__ pool,
                                            const float* __restrict__ vcnt,
                                            const int* __restrict__ slist,
                                            const int* __restrict__ scount,
                                            float* __restrict__ gm_out,
                                            float* __restrict__ has_out,
                                            int n_edges, int n_species,
                                            int n_gt) {
  __shared__ __attribute__((aligned(16))) float sPool[200 * 68];
  __shared__ float sValid[200];
  int g = blockIdx.x;
  int tid = threadIdx.x;
  const float* pg = pool + (size_t)g * n_species * 64;
  for (int i = tid; i < n_species * 64; i += 512)
    sPool[(i >> 6) * 68 + (i & 63)] = pg[i];
  for (int i = tid; i < n_species; i += 512)
    sValid[i] = vcnt[(size_t)g * n_species + i];
  __syncthreads();
  int w = tid >> 6, lane = tid & 63;
  int lq = lane & 15;
  int ngroups = (n_edges + 3) >> 2;
  for (int eg = w; eg < ngroups; eg += 8) {
    int e = eg * 4 + (lane >> 4);
    bool ev = e < n_edges;
    int nc = ev ? scount[e] : 0;
    int ncm = nc;
    ncm = max(ncm, __shfl_xor(ncm, 16));
    ncm = max(ncm, __shfl_xor(ncm, 32));
    const int* sl = slist + (size_t)(ev ? e : 0) * SMAX;
    float4 csum = {0.f, 0.f, 0.f, 0.f};
    float vc = 0.f;
    for (int c = 0; c < ncm; c += 16) {
      int j = c + lq;
      int r = (j < nc) ? sl[j] : 0;
      vc += (j < nc) ? sValid[r] : 0.f;
      int rem = nc - c;
      int lim = min(16, ncm - c);
      for (int i = 0; i < lim; ++i) {
        int s = __builtin_amdgcn_ds_bpermute(((lane & 48) | i) << 2, r);
        const float4 v =
            *reinterpret_cast<const float4*>(&sPool[s * 68 + lq * 4]);
        if (i < rem) {
          csum.x += v.x;
          csum.y += v.y;
          csum.z += v.z;
          csum.w += v.w;
        }
      }
    }
    vc += __shfl_xor(vc, 1);
    vc += __shfl_xor(vc, 2);
    vc += __shfl_xor(vc, 4);
    vc += __shfl_xor(vc, 8);
    if (ev) {
      float inv = 1.f / fmaxf(vc, 1.f);
      float4 gm = {csum.x * inv, csum.y * inv, csum.z * inv, csum.w * inv};
      *reinterpret_cast<float4*>(&gm_out[((size_t)e * n_gt + g) * 64 + lq * 4]) =
          gm;
      if (lq == 0) has_out[(size_t)e * n_gt + g] = (vc > 0.f) ? 1.f : 0.f;
    }
  }
}

// One block per species-tree edge: streaming mean/std over gene trees.
__global__ __launch_bounds__(512) void k_stat(const float* __restrict__ gmat,
                                              const float* __restrict__ has,
                                              float* __restrict__ out,
                                              int n_gt) {
  __shared__ float red1[8][64];
  __shared__ float red2[8][64];
  __shared__ float redn[8];
  int e = blockIdx.x;
  int tid = threadIdx.x, w = tid >> 6, lane = tid & 63;
  const float* ge = gmat + (size_t)e * n_gt * 64;
  const float* he = has + (size_t)e * n_gt;
  float S1 = 0.f, S2 = 0.f, nv = 0.f;
  for (int g = w; g < n_gt; g += 8) {
    float h = he[g];
    float v = ge[g * 64 + lane];
    S1 += h * v;
    S2 += h * v * v;
    nv += h;
  }
  red1[w][lane] = S1;
  red2[w][lane] = S2;
  if (lane == 0) redn[w] = nv;
  __syncthreads();
  if (w == 0) {
    float s1 = 0.f, s2 = 0.f, n_v = 0.f;
#pragma unroll
    for (int j = 0; j < 8; ++j) {
      s1 += red1[j][lane];
      s2 += red2[j][lane];
      n_v += redn[j];
    }
    float mean = s1 / fmaxf(n_v, 1.f);
    float var = (s2 - s1 * s1 / fmaxf(n_v, 1.f)) / fmaxf(n_v - 1.f, 1.f);
    float stdv = (n_v > 1.f) ? sqrtf(fmaxf(var, 0.f)) : 0.f;
    out[(size_t)e * 128 + lane] = (n_v > 0.f) ? mean : 0.f;
    out[(size_t)e * 128 + 64 + lane] = stdv;
  }
}

extern "C" void kernel_launch(void* const* d_in, const int* in_sizes, int n_in,
                              void* d_out, int out_size, void* d_ws, size_t ws_size,
                              hipStream_t stream) {
  (void)n_in; (void)out_size; (void)ws_size;
  const int* edge_index = (const int*)d_in[0];
  const int* sp_ids = (const int*)d_in[1];
  const int* leaf_mask = (const int*)d_in[2];
  const int* clade_mask = (const int*)d_in[4];
  const float* emb = (const float*)d_in[6];
  const float* W1 = (const float*)d_in[7];
  const float* b1 = (const float*)d_in[8];
  const float* W2 = (const float*)d_in[9];
  const float* b2 = (const float*)d_in[10];
  const float* eps = (const float*)d_in[11];
  const float* lng = (const float*)d_in[12];
  const float* lnb = (const float*)d_in[13];
  float* out = (float*)d_out;

  const int n_nodes = in_sizes[1];             // 204288
  const int nE = in_sizes[0] / 2;              // 407552 directed edges
  const int n_species = in_sizes[6] / 64 - 1;  // 200
  const int n_edges = in_sizes[4] / n_species; // 397
  const int L = in_sizes[11];                  // 2
  const int n_gt = 512;                        // fixed problem size
  const int npg = n_nodes / n_gt;              // 399 nodes per gene tree

  const int* src = edge_index;       // first half: child ids
  const int* dst = edge_index + nE;  // first half: parent ids

  float* x = (float*)d_ws;
  size_t xb = (size_t)n_nodes * 64 * sizeof(float);
  float* msg = (float*)((char*)d_ws + xb);
  float* pool = msg;  // msg region reused after GNN layers
  size_t poolb = (size_t)n_gt * n_species * 64 * sizeof(float);
  float* vcnt = (float*)((char*)pool + poolb);
  size_t cntb = (size_t)n_gt * n_species * sizeof(float);
  float* has = (float*)((char*)vcnt + cntb);
  size_t hasb = (size_t)n_edges * n_gt * sizeof(float);
  int* slist = (int*)((char*)has + hasb);
  int* scount = (int*)((char*)slist + (size_t)n_edges * SMAX * sizeof(int));
  float* gmat = x;  // x is dead after k_pool

  int embBlocks = (n_nodes * 16 + 255) / 256;
  k_embed<<<embBlocks, 256, 0, stream>>>(emb, sp_ids, x, n_nodes, n_species);

  int mlB = (n_nodes + 15) / 16;
  for (int l = 0; l < L; ++l) {
    k_msg<<<n_gt, 512, 0, stream>>>(x, msg, src, dst, npg);
    k_mlp<<<mlB, 256, 0, stream>>>(x, msg, W1 + l * 4096, b1 + l * 64,
                                   W2 + l * 4096, b2 + l * 64, eps + l,
                                   lng + l * 64, lnb + l * 64, x, n_nodes);
  }

  k_pool<<<n_gt, 256, 0, stream>>>(x, sp_ids, leaf_mask, pool, vcnt, npg,
                                   n_species);
  k_slist<<<(n_edges + 3) / 4, 256, 0, stream>>>(clade_mask, slist, scount,
                                                 n_edges, n_species);
  k_gm<<<n_gt, 512, 0, stream>>>(pool, vcnt, slist, scount, gmat, has,
                                 n_edges, n_species, n_gt);
  k_stat<<<n_edges, 512, 0, stream>>>(gmat, has, out, n_gt);
}

// Round 6
// 416.387 us; speedup vs baseline: 21.1433x; 1.2449x over previous
//
#include <hip/hip_runtime.h>

// Fixed problem geometry: D=64, n_gt=512, npg=399 nodes/tree, 398 edges/tree.
#define SMAX 200
#define NPG 399

typedef __bf16 bf16x8 __attribute__((ext_vector_type(8)));
typedef float f32x4 __attribute__((ext_vector_type(4)));

__device__ __forceinline__ float rl(float v, int l) {
  return __int_as_float(__builtin_amdgcn_readlane(__float_as_int(v), l));
}
__device__ __forceinline__ float wredsum(float v) {
  for (int off = 32; off; off >>= 1) v += __shfl_xor(v, off);
  return v;
}
__device__ __forceinline__ unsigned short f2bf(float f) {
  unsigned u = __float_as_uint(f);
  unsigned r = (u + 0x7FFFu + ((u >> 16) & 1u)) >> 16;
  return (unsigned short)r;
}

__global__ __launch_bounds__(256) void k_embed(const float* __restrict__ emb,
                                               const int* __restrict__ sp,
                                               float* __restrict__ x,
                                               int n_nodes, int n_species) {
  int t = blockIdx.x * 256 + threadIdx.x;
  int node = t >> 4, q = t & 15;
  if (node >= n_nodes) return;
  int s = sp[node];
  int row = (s < 0) ? n_species : s;
  reinterpret_cast<float4*>(x)[node * 16 + q] =
      reinterpret_cast<const float4*>(emb)[row * 16 + q];
}

// One block per gene tree. Stage x[tree] (102 KB) in LDS, build the child-CSR
// in LDS (histogram -> Hillis-Steele scan -> scatter), then each wave computes
// msg[i] = sum_children x[c] + x[par[i]] from LDS.
__global__ __launch_bounds__(512) void k_msg(const float* __restrict__ x,
                                             float* __restrict__ msg,
                                             const int* __restrict__ src,
                                             const int* __restrict__ dst,
                                             int npg) {
  __shared__ __attribute__((aligned(16))) float sX[NPG * 64];
  __shared__ int sStart[NPG + 1];
  __shared__ int sChild[NPG - 1];
  __shared__ int sPar[NPG];
  __shared__ int sCnt[NPG];
  int g = blockIdx.x;
  int tid = threadIdx.x;
  int nEt = npg - 1;
  int base = g * npg;
  int ebase = g * nEt;
  for (int i = tid; i < npg + 1; i += 512) sStart[i] = 0;
  for (int i = tid; i < npg; i += 512) sCnt[i] = 0;
  __syncthreads();
  const float4* xg4 = reinterpret_cast<const float4*>(x + (size_t)base * 64);
  for (int i = tid; i < npg * 16; i += 512)
    reinterpret_cast<float4*>(sX)[i] = xg4[i];
  for (int i = tid; i < nEt; i += 512) {
    int c = src[ebase + i] - base;
    int p = dst[ebase + i] - base;
    sPar[c] = p;
    atomicAdd(&sStart[p + 1], 1);
  }
  __syncthreads();
  for (int off = 1; off < npg + 1; off <<= 1) {
    int t = 0;
    if (tid < npg + 1 && tid >= off) t = sStart[tid - off];
    __syncthreads();
    if (tid < npg + 1 && tid >= off) sStart[tid] += t;
    __syncthreads();
  }
  for (int c = tid + 1; c < npg; c += 512) {
    int p = sPar[c];
    int pos = sStart[p] + atomicAdd(&sCnt[p], 1);
    sChild[pos] = c;
  }
  __syncthreads();
  int w = tid >> 6, lane = tid & 63;
  for (int i = w; i < npg; i += 8) {
    float s = 0.f;
    int j0 = sStart[i], j1 = sStart[i + 1];
    for (int j = j0; j < j1; ++j) s += sX[sChild[j] * 64 + lane];
    if (i > 0) s += sX[sPar[i] * 64 + lane];
    msg[(size_t)(base + i) * 64 + lane] = s;
  }
}

// 16 nodes/block, 4 nodes/wave (lane = output dim), readlane broadcast.
__global__ __launch_bounds__(256) void k_mlp(const float* __restrict__ x_in,
                                             const float* __restrict__ msg,
                                             const float* __restrict__ W1,
                                             const float* __restrict__ b1,
                                             const float* __restrict__ W2,
                                             const float* __restrict__ b2,
                                             const float* __restrict__ eps_p,
                                             const float* __restrict__ gam,
                                             const float* __restrict__ bet,
                                             float* __restrict__ x_out, int n) {
  __shared__ __attribute__((aligned(16))) float sW1[64 * 64];
  __shared__ __attribute__((aligned(16))) float sW2[64 * 64];
  __shared__ float sb1[64], sb2[64], sg[64], sb[64];
  int tid = threadIdx.x;
  for (int i = tid; i < 1024; i += 256) {
    reinterpret_cast<float4*>(sW1)[i] = reinterpret_cast<const float4*>(W1)[i];
    reinterpret_cast<float4*>(sW2)[i] = reinterpret_cast<const float4*>(W2)[i];
  }
  if (tid < 64) {
    sb1[tid] = b1[tid];
    sb2[tid] = b2[tid];
    sg[tid] = gam[tid];
    sb[tid] = bet[tid];
  }
  __syncthreads();
  int w = tid >> 6, lane = tid & 63;
  int base = blockIdx.x * 16 + w * 4;
  if (base >= n) return;
  float e1 = 1.0f + eps_p[0];
  const float* xr = x_in + (size_t)base * 64 + lane;
  const float* mr = msg + (size_t)base * 64 + lane;
  float xv0 = xr[0], xv1 = xr[64], xv2 = xr[128], xv3 = xr[192];
  float u0 = fmaf(e1, xv0, mr[0]);
  float u1 = fmaf(e1, xv1, mr[64]);
  float u2 = fmaf(e1, xv2, mr[128]);
  float u3 = fmaf(e1, xv3, mr[192]);
  float t0 = sb1[lane], t1 = t0, t2 = t0, t3 = t0;
#pragma unroll
  for (int k = 0; k < 64; ++k) {
    float wk = sW1[k * 64 + lane];
    t0 = fmaf(rl(u0, k), wk, t0);
    t1 = fmaf(rl(u1, k), wk, t1);
    t2 = fmaf(rl(u2, k), wk, t2);
    t3 = fmaf(rl(u3, k), wk, t3);
  }
  t0 = fmaxf(t0, 0.f);
  t1 = fmaxf(t1, 0.f);
  t2 = fmaxf(t2, 0.f);
  t3 = fmaxf(t3, 0.f);
  float h0 = sb2[lane], h1 = h0, h2 = h0, h3 = h0;
#pragma unroll
  for (int k = 0; k < 64; ++k) {
    float wk = sW2[k * 64 + lane];
    h0 = fmaf(rl(t0, k), wk, h0);
    h1 = fmaf(rl(t1, k), wk, h1);
    h2 = fmaf(rl(t2, k), wk, h2);
    h3 = fmaf(rl(t3, k), wk, h3);
  }
  float g = sg[lane], bb = sb[lane];
  float* xo = x_out + (size_t)base * 64 + lane;
  {
    float y = xv0 + h0;
    float mu = wredsum(y) * (1.f / 64.f);
    float d0 = y - mu;
    float v = wredsum(d0 * d0) * (1.f / 64.f);
    xo[0] = d0 * rsqrtf(v + 1e-5f) * g + bb;
  }
  {
    float y = xv1 + h1;
    float mu = wredsum(y) * (1.f / 64.f);
    float d0 = y - mu;
    float v = wredsum(d0 * d0) * (1.f / 64.f);
    xo[64] = d0 * rsqrtf(v + 1e-5f) * g + bb;
  }
  {
    float y = xv2 + h2;
    float mu = wredsum(y) * (1.f / 64.f);
    float d0 = y - mu;
    float v = wredsum(d0 * d0) * (1.f / 64.f);
    xo[128] = d0 * rsqrtf(v + 1e-5f) * g + bb;
  }
  {
    float y = xv3 + h3;
    float mu = wredsum(y) * (1.f / 64.f);
    float d0 = y - mu;
    float v = wredsum(d0 * d0) * (1.f / 64.f);
    xo[192] = d0 * rsqrtf(v + 1e-5f) * g + bb;
  }
}

// Build A-operand fragments (mf as bf16, pre-swizzled into the 16x16x32 MFMA
// lane layout: A row = lane&15, k = (lane>>4)*8+j) and packed mf bitmasks.
__global__ __launch_bounds__(256) void k_prep(const int* __restrict__ clade,
                                              unsigned short* __restrict__ mfA,
                                              unsigned* __restrict__ mfbits,
                                              int n_edges, int n_species) {
  int stride = gridDim.x * 256;
  for (int idx = blockIdx.x * 256 + threadIdx.x; idx < 25 * 7 * 512;
       idx += stride) {
    int fi = idx >> 9, within = idx & 511;
    int mt = fi / 7, kt = fi % 7;
    int l = within >> 3, j = within & 7;
    int e = mt * 16 + (l & 15);
    int s = kt * 32 + ((l >> 4) & 3) * 8 + j;
    unsigned short v = 0;
    if (e < n_edges && s < n_species && clade[(size_t)e * n_species + s] != 0)
      v = 0x3F80;  // bf16(1.0)
    mfA[idx] = v;
  }
  for (int idx = blockIdx.x * 256 + threadIdx.x; idx < 400 * 8; idx += stride) {
    int e = idx >> 3, w = idx & 7;
    unsigned bits = 0;
    if (e < n_edges && w < 7) {
      for (int b = 0; b < 32; ++b) {
        int s = w * 32 + b;
        if (s < n_species && clade[(size_t)e * n_species + s] != 0)
          bits |= 1u << b;
      }
    }
    mfbits[idx] = bits;
  }
}

// Species pooling: block per gene tree, LDS accumulation, then write
// (a) pool as bf16 fragment-swizzled B-operand blocks [28KB per tree]
// (b) packed valid bitmask per tree. Invalid (g,s) rows are zero.
__global__ __launch_bounds__(256) void k_pool(const float* __restrict__ x,
                                              const int* __restrict__ sp,
                                              const int* __restrict__ leaf,
                                              unsigned short* __restrict__ pool_swz,
                                              unsigned* __restrict__ valid_bits,
                                              int npg, int n_species) {
  __shared__ __attribute__((aligned(16))) float acc[200 * 64];
  __shared__ float cnt[200];
  int g = blockIdx.x;
  int tid = threadIdx.x;
  for (int i = tid; i < n_species * 64; i += 256) acc[i] = 0.f;
  for (int i = tid; i < n_species; i += 256) cnt[i] = 0.f;
  __syncthreads();
  int w = tid >> 6, lane = tid & 63;
  for (int i = w; i < npg; i += 4) {
    int node = g * npg + i;
    int s = sp[node];
    if (s >= 0 && leaf[node]) {
      atomicAdd(&acc[s * 64 + lane], x[(size_t)node * 64 + lane]);
      if (lane == 0) atomicAdd(&cnt[s], 1.f);
    }
  }
  __syncthreads();
  if (tid < 8) {
    unsigned bits = 0;
    if (tid < 7) {
      for (int b = 0; b < 32; ++b) {
        int s = tid * 32 + b;
        if (s < n_species && cnt[s] > 0.f) bits |= 1u << b;
      }
    }
    valid_bits[(size_t)g * 8 + tid] = bits;
  }
  unsigned short* pg = pool_swz + (size_t)g * 14336;
  for (int idx = tid; idx < 224 * 64; idx += 256) {
    int s = idx >> 6, d = idx & 63;
    float v = 0.f;
    if (s < n_species) v = acc[s * 64 + d] / fmaxf(cnt[s], 1.f);
    int frag = (s >> 5) * 4 + (d >> 4);
    int lane2 = ((s >> 3) & 3) * 16 + (d & 15);
    int j = s & 7;
    pg[frag * 512 + lane2 * 8 + j] = f2bf(v);
  }
}

// MFMA clade-sum: one WG per gene tree g. C[e][d] = sum_s mf[e][s]*pool[g][s][d]
// via 16x16x32 bf16 MFMA; epilogue divides by ccnt (exact, popcount of
// mf_bits & valid_bits) and writes gm [e][g][d] + has [e][g].
__global__ __launch_bounds__(512) void k_gm2(const unsigned short* __restrict__ pool_swz,
                                             const unsigned* __restrict__ valid_bits,
                                             const unsigned short* __restrict__ mfA,
                                             const unsigned* __restrict__ mfbits,
                                             float* __restrict__ gmat,
                                             float* __restrict__ has,
                                             int n_edges, int n_gt) {
  __shared__ __attribute__((aligned(16))) unsigned short sBf[14336];
  __shared__ float sInv[400];
  __shared__ float sHas[400];
  int g = blockIdx.x;
  int tid = threadIdx.x;
  const float4* src4 =
      reinterpret_cast<const float4*>(pool_swz + (size_t)g * 14336);
  float4* dst4 = reinterpret_cast<float4*>(sBf);
  for (int i = tid; i < 1792; i += 512) dst4[i] = src4[i];
  unsigned vb[7];
#pragma unroll
  for (int w2 = 0; w2 < 7; ++w2) vb[w2] = valid_bits[(size_t)g * 8 + w2];
  for (int e = tid; e < 400; e += 512) {
    unsigned cc = 0;
#pragma unroll
    for (int w2 = 0; w2 < 7; ++w2) cc += __popc(mfbits[e * 8 + w2] & vb[w2]);
    sInv[e] = 1.f / (float)max(cc, 1u);
    sHas[e] = (cc > 0) ? 1.f : 0.f;
  }
  __syncthreads();
  int w = tid >> 6, lane = tid & 63;
  const bf16x8* A = reinterpret_cast<const bf16x8*>(mfA);
  const bf16x8* Bb = reinterpret_cast<const bf16x8*>(sBf);
  for (int mt = w; mt < 25; mt += 8) {
    bf16x8 af[7];
#pragma unroll
    for (int kt = 0; kt < 7; ++kt) af[kt] = A[(mt * 7 + kt) * 64 + lane];
    f32x4 acc0 = {0.f, 0.f, 0.f, 0.f};
    f32x4 acc1 = {0.f, 0.f, 0.f, 0.f};
    f32x4 acc2 = {0.f, 0.f, 0.f, 0.f};
    f32x4 acc3 = {0.f, 0.f, 0.f, 0.f};
#pragma unroll
    for (int kt = 0; kt < 7; ++kt) {
      const bf16x8* B = Bb + kt * 256 + lane;
      acc0 = __builtin_amdgcn_mfma_f32_16x16x32_bf16(af[kt], B[0], acc0, 0, 0, 0);
      acc1 = __builtin_amdgcn_mfma_f32_16x16x32_bf16(af[kt], B[64], acc1, 0, 0, 0);
      acc2 = __builtin_amdgcn_mfma_f32_16x16x32_bf16(af[kt], B[128], acc2, 0, 0, 0);
      acc3 = __builtin_amdgcn_mfma_f32_16x16x32_bf16(af[kt], B[192], acc3, 0, 0, 0);
    }
    int rbase = mt * 16 + (lane >> 4) * 4;
    int col = lane & 15;
#pragma unroll
    for (int r = 0; r < 4; ++r) {
      int e = rbase + r;
      if (e >= n_edges) continue;
      float inv = sInv[e];
      float* gp = gmat + ((size_t)e * n_gt + g) * 64 + col;
      gp[0] = acc0[r] * inv;
      gp[16] = acc1[r] * inv;
      gp[32] = acc2[r] * inv;
      gp[48] = acc3[r] * inv;
      if (col == 0) has[(size_t)e * n_gt + g] = sHas[e];
    }
  }
}

// One block per species-tree edge: streaming mean/std over gene trees.
__global__ __launch_bounds__(512) void k_stat(const float* __restrict__ gmat,
                                              const float* __restrict__ has,
                                              float* __restrict__ out,
                                              int n_gt) {
  __shared__ float red1[8][64];
  __shared__ float red2[8][64];
  __shared__ float redn[8];
  int e = blockIdx.x;
  int tid = threadIdx.x, w = tid >> 6, lane = tid & 63;
  const float* ge = gmat + (size_t)e * n_gt * 64;
  const float* he = has + (size_t)e * n_gt;
  float S1 = 0.f, S2 = 0.f, nv = 0.f;
  for (int g = w; g < n_gt; g += 8) {
    float h = he[g];
    float v = ge[g * 64 + lane];
    S1 += h * v;
    S2 += h * v * v;
    nv += h;
  }
  red1[w][lane] = S1;
  red2[w][lane] = S2;
  if (lane == 0) redn[w] = nv;
  __syncthreads();
  if (w == 0) {
    float s1 = 0.f, s2 = 0.f, n_v = 0.f;
#pragma unroll
    for (int j = 0; j < 8; ++j) {
      s1 += red1[j][lane];
      s2 += red2[j][lane];
      n_v += redn[j];
    }
    float mean = s1 / fmaxf(n_v, 1.f);
    float var = (s2 - s1 * s1 / fmaxf(n_v, 1.f)) / fmaxf(n_v - 1.f, 1.f);
    float stdv = (n_v > 1.f) ? sqrtf(fmaxf(var, 0.f)) : 0.f;
    out[(size_t)e * 128 + lane] = (n_v > 0.f) ? mean : 0.f;
    out[(size_t)e * 128 + 64 + lane] = stdv;
  }
}

extern "C" void kernel_launch(void* const* d_in, const int* in_sizes, int n_in,
                              void* d_out, int out_size, void* d_ws, size_t ws_size,
                              hipStream_t stream) {
  (void)n_in; (void)out_size; (void)ws_size;
  const int* edge_index = (const int*)d_in[0];
  const int* sp_ids = (const int*)d_in[1];
  const int* leaf_mask = (const int*)d_in[2];
  const int* clade_mask = (const int*)d_in[4];
  const float* emb = (const float*)d_in[6];
  const float* W1 = (const float*)d_in[7];
  const float* b1 = (const float*)d_in[8];
  const float* W2 = (const float*)d_in[9];
  const float* b2 = (const float*)d_in[10];
  const float* eps = (const float*)d_in[11];
  const float* lng = (const float*)d_in[12];
  const float* lnb = (const float*)d_in[13];
  float* out = (float*)d_out;

  const int n_nodes = in_sizes[1];             // 204288
  const int nE = in_sizes[0] / 2;              // 407552 directed edges
  const int n_species = in_sizes[6] / 64 - 1;  // 200
  const int n_edges = in_sizes[4] / n_species; // 397
  const int L = in_sizes[11];                  // 2
  const int n_gt = 512;                        // fixed problem size
  const int npg = n_nodes / n_gt;              // 399 nodes per gene tree

  const int* src = edge_index;       // first half: child ids
  const int* dst = edge_index + nE;  // first half: parent ids

  float* x = (float*)d_ws;
  size_t xb = (size_t)n_nodes * 64 * sizeof(float);
  char* r1 = (char*)d_ws + xb;
  unsigned short* pool_swz = (unsigned short*)r1;
  size_t psz = (size_t)n_gt * 14336 * sizeof(unsigned short);  // 14,680,064
  unsigned* valid_bits = (unsigned*)(r1 + psz);
  size_t vbsz = (size_t)n_gt * 8 * sizeof(unsigned);  // 16,384
  unsigned short* mfA = (unsigned short*)(r1 + psz + vbsz);
  size_t masz = (size_t)25 * 7 * 512 * sizeof(unsigned short);  // 179,200
  unsigned* mfbits = (unsigned*)(r1 + psz + vbsz + masz);
  size_t mbsz = (size_t)400 * 8 * sizeof(unsigned);  // 12,800
  float* has = (float*)(r1 + psz + vbsz + masz + mbsz);
  float* msg = (float*)(r1 + psz + vbsz + masz + mbsz +
                        ((size_t)n_edges * n_gt * sizeof(float) + 255ul & ~255ul));
  float* gmat = x;  // x region reused after k_pool

  k_prep<<<64, 256, 0, stream>>>(clade_mask, mfA, mfbits, n_edges, n_species);

  int embBlocks = (n_nodes * 16 + 255) / 256;
  k_embed<<<embBlocks, 256, 0, stream>>>(emb, sp_ids, x, n_nodes, n_species);

  int mlB = (n_nodes + 15) / 16;
  for (int l = 0; l < L; ++l) {
    k_msg<<<n_gt, 512, 0, stream>>>(x, msg, src, dst, npg);
    k_mlp<<<mlB, 256, 0, stream>>>(x, msg, W1 + l * 4096, b1 + l * 64,
                                   W2 + l * 4096, b2 + l * 64, eps + l,
                                   lng + l * 64, lnb + l * 64, x, n_nodes);
  }

  k_pool<<<n_gt, 256, 0, stream>>>(x, sp_ids, leaf_mask, pool_swz, valid_bits,
                                   npg, n_species);
  k_gm2<<<n_gt, 512, 0, stream>>>(pool_swz, valid_bits, mfA, mfbits, gmat, has,
                                  n_edges, n_gt);
  k_stat<<<n_edges, 512, 0, stream>>>(gmat, has, out, n_gt);
}

// Round 7
// 299.860 us; speedup vs baseline: 29.3598x; 1.3886x over previous
//
#include <hip/hip_runtime.h>

// Fixed problem geometry: D=64, n_gt=512, npg=399 nodes/tree, 398 edges/tree.
#define SMAX 200
#define NPG 399

typedef __bf16 bf16x8 __attribute__((ext_vector_type(8)));
typedef _Float16 half8 __attribute__((ext_vector_type(8)));
typedef float f32x4 __attribute__((ext_vector_type(4)));

__device__ __forceinline__ float wredsum(float v) {
  for (int off = 32; off; off >>= 1) v += __shfl_xor(v, off);
  return v;
}
__device__ __forceinline__ unsigned short f2bf(float f) {
  unsigned u = __float_as_uint(f);
  unsigned r = (u + 0x7FFFu + ((u >> 16) & 1u)) >> 16;
  return (unsigned short)r;
}

__global__ __launch_bounds__(256) void k_embed(const float* __restrict__ emb,
                                               const int* __restrict__ sp,
                                               float* __restrict__ x,
                                               int n_nodes, int n_species) {
  int t = blockIdx.x * 256 + threadIdx.x;
  int node = t >> 4, q = t & 15;
  if (node >= n_nodes) return;
  int s = sp[node];
  int row = (s < 0) ? n_species : s;
  reinterpret_cast<float4*>(x)[node * 16 + q] =
      reinterpret_cast<const float4*>(emb)[row * 16 + q];
}

// One block per gene tree. Stage x[tree] (102 KB) in LDS, build the child-CSR
// in LDS (histogram -> Hillis-Steele scan -> scatter), then each wave computes
// msg[i] = sum_children x[c] + x[par[i]] from LDS.
__global__ __launch_bounds__(512) void k_msg(const float* __restrict__ x,
                                             float* __restrict__ msg,
                                             const int* __restrict__ src,
                                             const int* __restrict__ dst,
                                             int npg) {
  __shared__ __attribute__((aligned(16))) float sX[NPG * 64];
  __shared__ int sStart[NPG + 1];
  __shared__ int sChild[NPG - 1];
  __shared__ int sPar[NPG];
  __shared__ int sCnt[NPG];
  int g = blockIdx.x;
  int tid = threadIdx.x;
  int nEt = npg - 1;
  int base = g * npg;
  int ebase = g * nEt;
  for (int i = tid; i < npg + 1; i += 512) sStart[i] = 0;
  for (int i = tid; i < npg; i += 512) sCnt[i] = 0;
  __syncthreads();
  const float4* xg4 = reinterpret_cast<const float4*>(x + (size_t)base * 64);
  for (int i = tid; i < npg * 16; i += 512)
    reinterpret_cast<float4*>(sX)[i] = xg4[i];
  for (int i = tid; i < nEt; i += 512) {
    int c = src[ebase + i] - base;
    int p = dst[ebase + i] - base;
    sPar[c] = p;
    atomicAdd(&sStart[p + 1], 1);
  }
  __syncthreads();
  for (int off = 1; off < npg + 1; off <<= 1) {
    int t = 0;
    if (tid < npg + 1 && tid >= off) t = sStart[tid - off];
    __syncthreads();
    if (tid < npg + 1 && tid >= off) sStart[tid] += t;
    __syncthreads();
  }
  for (int c = tid + 1; c < npg; c += 512) {
    int p = sPar[c];
    int pos = sStart[p] + atomicAdd(&sCnt[p], 1);
    sChild[pos] = c;
  }
  __syncthreads();
  int w = tid >> 6, lane = tid & 63;
  for (int i = w; i < npg; i += 8) {
    float s = 0.f;
    int j0 = sStart[i], j1 = sStart[i + 1];
    for (int j = j0; j < j1; ++j) s += sX[sChild[j] * 64 + lane];
    if (i > 0) s += sX[sPar[i] * 64 + lane];
    msg[(size_t)(base + i) * 64 + lane] = s;
  }
}

// MFMA MLP: 256 threads = 4 waves x 16 nodes. u=(1+eps)x+msg cast to f16,
// W1/W2 fragment-swizzled f16 in LDS; 2x (2 K-frags x 4 N-frags) MFMA
// 16x16x32_f16; relu+bias between; residual + LayerNorm in f32.
// Fragment maps HW-verified by k_gm2 (round 6): A m=lane&15,k=(lane>>4)*8+j;
// B n=lane&15 same k; C m=(lane>>4)*4+r, n=(lane&15)+16*nt.
__global__ __launch_bounds__(256) void k_mlp2(const float* __restrict__ x_io,
                                              const float* __restrict__ msg,
                                              const float* __restrict__ W1,
                                              const float* __restrict__ b1,
                                              const float* __restrict__ W2,
                                              const float* __restrict__ b2,
                                              const float* __restrict__ eps_p,
                                              const float* __restrict__ gam,
                                              const float* __restrict__ bet,
                                              float* __restrict__ x_out) {
  __shared__ __attribute__((aligned(16))) _Float16 sWf[2][4096];
  __shared__ __attribute__((aligned(16))) float sXt[4][16 * 72];
  __shared__ __attribute__((aligned(16))) float sUt[4][16 * 72];
  int tid = threadIdx.x;
  for (int idx = tid; idx < 4096; idx += 256) {
    int k = idx >> 6, n = idx & 63;
    int frag = (k >> 5) * 4 + (n >> 4);
    int ln = ((k >> 3) & 3) * 16 + (n & 15);
    int j = k & 7;
    sWf[0][frag * 512 + ln * 8 + j] = (_Float16)W1[idx];
    sWf[1][frag * 512 + ln * 8 + j] = (_Float16)W2[idx];
  }
  __syncthreads();
  int w = tid >> 6, lane = tid & 63;
  int g = lane >> 4, c = lane & 15;
  float e1 = 1.0f + eps_p[0];
  int tb = blockIdx.x * 64 + w * 16;
  float b1v[4], b2v[4], gv[4], bv[4];
#pragma unroll
  for (int nt = 0; nt < 4; ++nt) {
    b1v[nt] = b1[c + 16 * nt];
    b2v[nt] = b2[c + 16 * nt];
    gv[nt] = gam[c + 16 * nt];
    bv[nt] = bet[c + 16 * nt];
  }
  float* xt = sXt[w];
  float* ut = sUt[w];
#pragma unroll
  for (int it = 0; it < 4; ++it) {
    int m = it * 4 + g;
    float4 xv = reinterpret_cast<const float4*>(x_io)[(size_t)(tb + m) * 16 + c];
    float4 mv = reinterpret_cast<const float4*>(msg)[(size_t)(tb + m) * 16 + c];
    float4 uv;
    uv.x = fmaf(e1, xv.x, mv.x);
    uv.y = fmaf(e1, xv.y, mv.y);
    uv.z = fmaf(e1, xv.z, mv.z);
    uv.w = fmaf(e1, xv.w, mv.w);
    *reinterpret_cast<float4*>(&xt[m * 72 + c * 4]) = xv;
    *reinterpret_cast<float4*>(&ut[m * 72 + c * 4]) = uv;
  }
  // ---- matvec 1: t = relu(u @ W1 + b1) ----
  half8 a1[2];
#pragma unroll
  for (int kt = 0; kt < 2; ++kt) {
    int k0 = kt * 32 + g * 8;
    float4 p0 = *reinterpret_cast<const float4*>(&ut[c * 72 + k0]);
    float4 p1 = *reinterpret_cast<const float4*>(&ut[c * 72 + k0 + 4]);
    half8 a;
    a[0] = (_Float16)p0.x; a[1] = (_Float16)p0.y;
    a[2] = (_Float16)p0.z; a[3] = (_Float16)p0.w;
    a[4] = (_Float16)p1.x; a[5] = (_Float16)p1.y;
    a[6] = (_Float16)p1.z; a[7] = (_Float16)p1.w;
    a1[kt] = a;
  }
  const half8* B1 = reinterpret_cast<const half8*>(sWf[0]);
  f32x4 tacc[4];
#pragma unroll
  for (int nt = 0; nt < 4; ++nt) tacc[nt] = (f32x4){0.f, 0.f, 0.f, 0.f};
#pragma unroll
  for (int kt = 0; kt < 2; ++kt)
#pragma unroll
    for (int nt = 0; nt < 4; ++nt)
      tacc[nt] = __builtin_amdgcn_mfma_f32_16x16x32_f16(
          a1[kt], B1[(kt * 4 + nt) * 64 + lane], tacc[nt], 0, 0, 0);
#pragma unroll
  for (int nt = 0; nt < 4; ++nt)
#pragma unroll
    for (int r = 0; r < 4; ++r)
      ut[(g * 4 + r) * 72 + c + 16 * nt] = fmaxf(tacc[nt][r] + b1v[nt], 0.f);
  // ---- matvec 2: h = t @ W2 + b2 ----
  half8 a2[2];
#pragma unroll
  for (int kt = 0; kt < 2; ++kt) {
    int k0 = kt * 32 + g * 8;
    float4 p0 = *reinterpret_cast<const float4*>(&ut[c * 72 + k0]);
    float4 p1 = *reinterpret_cast<const float4*>(&ut[c * 72 + k0 + 4]);
    half8 a;
    a[0] = (_Float16)p0.x; a[1] = (_Float16)p0.y;
    a[2] = (_Float16)p0.z; a[3] = (_Float16)p0.w;
    a[4] = (_Float16)p1.x; a[5] = (_Float16)p1.y;
    a[6] = (_Float16)p1.z; a[7] = (_Float16)p1.w;
    a2[kt] = a;
  }
  const half8* B2 = reinterpret_cast<const half8*>(sWf[1]);
  f32x4 hacc[4];
#pragma unroll
  for (int nt = 0; nt < 4; ++nt) hacc[nt] = (f32x4){0.f, 0.f, 0.f, 0.f};
#pragma unroll
  for (int kt = 0; kt < 2; ++kt)
#pragma unroll
    for (int nt = 0; nt < 4; ++nt)
      hacc[nt] = __builtin_amdgcn_mfma_f32_16x16x32_f16(
          a2[kt], B2[(kt * 4 + nt) * 64 + lane], hacc[nt], 0, 0, 0);
  // ---- residual + LayerNorm (f32) ----
  float y[4][4];  // [r][nt]
#pragma unroll
  for (int r = 0; r < 4; ++r)
#pragma unroll
    for (int nt = 0; nt < 4; ++nt)
      y[r][nt] = xt[(g * 4 + r) * 72 + c + 16 * nt] + hacc[nt][r] + b2v[nt];
  float mu[4], iv[4];
#pragma unroll
  for (int r = 0; r < 4; ++r) {
    float s = y[r][0] + y[r][1] + y[r][2] + y[r][3];
    s += __shfl_xor(s, 1);
    s += __shfl_xor(s, 2);
    s += __shfl_xor(s, 4);
    s += __shfl_xor(s, 8);
    mu[r] = s * (1.f / 64.f);
    float d0 = y[r][0] - mu[r], d1 = y[r][1] - mu[r];
    float d2 = y[r][2] - mu[r], d3 = y[r][3] - mu[r];
    float v = d0 * d0 + d1 * d1 + d2 * d2 + d3 * d3;
    v += __shfl_xor(v, 1);
    v += __shfl_xor(v, 2);
    v += __shfl_xor(v, 4);
    v += __shfl_xor(v, 8);
    iv[r] = rsqrtf(v * (1.f / 64.f) + 1e-5f);
  }
#pragma unroll
  for (int r = 0; r < 4; ++r)
#pragma unroll
    for (int nt = 0; nt < 4; ++nt)
      x_out[(size_t)(tb + g * 4 + r) * 64 + c + 16 * nt] =
          (y[r][nt] - mu[r]) * iv[r] * gv[nt] + bv[nt];
}

// Build A-operand fragments (mf as bf16, pre-swizzled into the 16x16x32 MFMA
// lane layout) and packed mf bitmasks.
__global__ __launch_bounds__(256) void k_prep(const int* __restrict__ clade,
                                              unsigned short* __restrict__ mfA,
                                              unsigned* __restrict__ mfbits,
                                              int n_edges, int n_species) {
  int stride = gridDim.x * 256;
  for (int idx = blockIdx.x * 256 + threadIdx.x; idx < 25 * 7 * 512;
       idx += stride) {
    int fi = idx >> 9, within = idx & 511;
    int mt = fi / 7, kt = fi % 7;
    int l = within >> 3, j = within & 7;
    int e = mt * 16 + (l & 15);
    int s = kt * 32 + ((l >> 4) & 3) * 8 + j;
    unsigned short v = 0;
    if (e < n_edges && s < n_species && clade[(size_t)e * n_species + s] != 0)
      v = 0x3F80;  // bf16(1.0)
    mfA[idx] = v;
  }
  for (int idx = blockIdx.x * 256 + threadIdx.x; idx < 400 * 8; idx += stride) {
    int e = idx >> 3, w = idx & 7;
    unsigned bits = 0;
    if (e < 397 && w < 7) {
      for (int b = 0; b < 32; ++b) {
        int s = w * 32 + b;
        if (s < n_species && clade[(size_t)e * n_species + s] != 0)
          bits |= 1u << b;
      }
    }
    mfbits[idx] = bits;
  }
}

// Species pooling: block per gene tree, LDS accumulation, then write
// (a) pool as bf16 fragment-swizzled B-operand blocks (b) packed valid bits.
__global__ __launch_bounds__(256) void k_pool(const float* __restrict__ x,
                                              const int* __restrict__ sp,
                                              const int* __restrict__ leaf,
                                              unsigned short* __restrict__ pool_swz,
                                              unsigned* __restrict__ valid_bits,
                                              int npg, int n_species) {
  __shared__ __attribute__((aligned(16))) float acc[200 * 64];
  __shared__ float cnt[200];
  int g = blockIdx.x;
  int tid = threadIdx.x;
  for (int i = tid; i < n_species * 64; i += 256) acc[i] = 0.f;
  for (int i = tid; i < n_species; i += 256) cnt[i] = 0.f;
  __syncthreads();
  int w = tid >> 6, lane = tid & 63;
  for (int i = w; i < npg; i += 4) {
    int node = g * npg + i;
    int s = sp[node];
    if (s >= 0 && leaf[node]) {
      atomicAdd(&acc[s * 64 + lane], x[(size_t)node * 64 + lane]);
      if (lane == 0) atomicAdd(&cnt[s], 1.f);
    }
  }
  __syncthreads();
  if (tid < 8) {
    unsigned bits = 0;
    if (tid < 7) {
      for (int b = 0; b < 32; ++b) {
        int s = tid * 32 + b;
        if (s < n_species && cnt[s] > 0.f) bits |= 1u << b;
      }
    }
    valid_bits[(size_t)g * 8 + tid] = bits;
  }
  unsigned short* pg = pool_swz + (size_t)g * 14336;
  for (int idx = tid; idx < 224 * 64; idx += 256) {
    int s = idx >> 6, d = idx & 63;
    float v = 0.f;
    if (s < n_species) v = acc[s * 64 + d] / fmaxf(cnt[s], 1.f);
    int frag = (s >> 5) * 4 + (d >> 4);
    int lane2 = ((s >> 3) & 3) * 16 + (d & 15);
    int j = s & 7;
    pg[frag * 512 + lane2 * 8 + j] = f2bf(v);
  }
}

// MFMA clade-sum: one WG per gene tree g.
__global__ __launch_bounds__(512) void k_gm2(const unsigned short* __restrict__ pool_swz,
                                             const unsigned* __restrict__ valid_bits,
                                             const unsigned short* __restrict__ mfA,
                                             const unsigned* __restrict__ mfbits,
                                             float* __restrict__ gmat,
                                             float* __restrict__ has,
                                             int n_edges, int n_gt) {
  __shared__ __attribute__((aligned(16))) unsigned short sBf[14336];
  __shared__ float sInv[400];
  __shared__ float sHas[400];
  int g = blockIdx.x;
  int tid = threadIdx.x;
  const float4* src4 =
      reinterpret_cast<const float4*>(pool_swz + (size_t)g * 14336);
  float4* dst4 = reinterpret_cast<float4*>(sBf);
  for (int i = tid; i < 1792; i += 512) dst4[i] = src4[i];
  unsigned vb[7];
#pragma unroll
  for (int w2 = 0; w2 < 7; ++w2) vb[w2] = valid_bits[(size_t)g * 8 + w2];
  for (int e = tid; e < 400; e += 512) {
    unsigned cc = 0;
#pragma unroll
    for (int w2 = 0; w2 < 7; ++w2) cc += __popc(mfbits[e * 8 + w2] & vb[w2]);
    sInv[e] = 1.f / (float)max(cc, 1u);
    sHas[e] = (cc > 0) ? 1.f : 0.f;
  }
  __syncthreads();
  int w = tid >> 6, lane = tid & 63;
  const bf16x8* A = reinterpret_cast<const bf16x8*>(mfA);
  const bf16x8* Bb = reinterpret_cast<const bf16x8*>(sBf);
  for (int mt = w; mt < 25; mt += 8) {
    bf16x8 af[7];
#pragma unroll
    for (int kt = 0; kt < 7; ++kt) af[kt] = A[(mt * 7 + kt) * 64 + lane];
    f32x4 acc0 = {0.f, 0.f, 0.f, 0.f};
    f32x4 acc1 = {0.f, 0.f, 0.f, 0.f};
    f32x4 acc2 = {0.f, 0.f, 0.f, 0.f};
    f32x4 acc3 = {0.f, 0.f, 0.f, 0.f};
#pragma unroll
    for (int kt = 0; kt < 7; ++kt) {
      const bf16x8* B = Bb + kt * 256 + lane;
      acc0 = __builtin_amdgcn_mfma_f32_16x16x32_bf16(af[kt], B[0], acc0, 0, 0, 0);
      acc1 = __builtin_amdgcn_mfma_f32_16x16x32_bf16(af[kt], B[64], acc1, 0, 0, 0);
      acc2 = __builtin_amdgcn_mfma_f32_16x16x32_bf16(af[kt], B[128], acc2, 0, 0, 0);
      acc3 = __builtin_amdgcn_mfma_f32_16x16x32_bf16(af[kt], B[192], acc3, 0, 0, 0);
    }
    int rbase = mt * 16 + (lane >> 4) * 4;
    int col = lane & 15;
#pragma unroll
    for (int r = 0; r < 4; ++r) {
      int e = rbase + r;
      if (e >= n_edges) continue;
      float inv = sInv[e];
      float* gp = gmat + ((size_t)e * n_gt + g) * 64 + col;
      gp[0] = acc0[r] * inv;
      gp[16] = acc1[r] * inv;
      gp[32] = acc2[r] * inv;
      gp[48] = acc3[r] * inv;
      if (col == 0) has[(size_t)e * n_gt + g] = sHas[e];
    }
  }
}

// One block per species-tree edge: streaming mean/std over gene trees.
__global__ __launch_bounds__(512) void k_stat(const float* __restrict__ gmat,
                                              const float* __restrict__ has,
                                              float* __restrict__ out,
                                              int n_gt) {
  __shared__ float red1[8][64];
  __shared__ float red2[8][64];
  __shared__ float redn[8];
  int e = blockIdx.x;
  int tid = threadIdx.x, w = tid >> 6, lane = tid & 63;
  const float* ge = gmat + (size_t)e * n_gt * 64;
  const float* he = has + (size_t)e * n_gt;
  float S1 = 0.f, S2 = 0.f, nv = 0.f;
  for (int g = w; g < n_gt; g += 8) {
    float h = he[g];
    float v = ge[g * 64 + lane];
    S1 += h * v;
    S2 += h * v * v;
    nv += h;
  }
  red1[w][lane] = S1;
  red2[w][lane] = S2;
  if (lane == 0) redn[w] = nv;
  __syncthreads();
  if (w == 0) {
    float s1 = 0.f, s2 = 0.f, n_v = 0.f;
#pragma unroll
    for (int j = 0; j < 8; ++j) {
      s1 += red1[j][lane];
      s2 += red2[j][lane];
      n_v += redn[j];
    }
    float mean = s1 / fmaxf(n_v, 1.f);
    float var = (s2 - s1 * s1 / fmaxf(n_v, 1.f)) / fmaxf(n_v - 1.f, 1.f);
    float stdv = (n_v > 1.f) ? sqrtf(fmaxf(var, 0.f)) : 0.f;
    out[(size_t)e * 128 + lane] = (n_v > 0.f) ? mean : 0.f;
    out[(size_t)e * 128 + 64 + lane] = stdv;
  }
}

extern "C" void kernel_launch(void* const* d_in, const int* in_sizes, int n_in,
                              void* d_out, int out_size, void* d_ws, size_t ws_size,
                              hipStream_t stream) {
  (void)n_in; (void)out_size; (void)ws_size;
  const int* edge_index = (const int*)d_in[0];
  const int* sp_ids = (const int*)d_in[1];
  const int* leaf_mask = (const int*)d_in[2];
  const int* clade_mask = (const int*)d_in[4];
  const float* emb = (const float*)d_in[6];
  const float* W1 = (const float*)d_in[7];
  const float* b1 = (const float*)d_in[8];
  const float* W2 = (const float*)d_in[9];
  const float* b2 = (const float*)d_in[10];
  const float* eps = (const float*)d_in[11];
  const float* lng = (const float*)d_in[12];
  const float* lnb = (const float*)d_in[13];
  float* out = (float*)d_out;

  const int n_nodes = in_sizes[1];             // 204288
  const int nE = in_sizes[0] / 2;              // 407552 directed edges
  const int n_species = in_sizes[6] / 64 - 1;  // 200
  const int n_edges = in_sizes[4] / n_species; // 397
  const int L = in_sizes[11];                  // 2
  const int n_gt = 512;                        // fixed problem size
  const int npg = n_nodes / n_gt;              // 399 nodes per gene tree

  const int* src = edge_index;       // first half: child ids
  const int* dst = edge_index + nE;  // first half: parent ids

  float* x = (float*)d_ws;
  size_t xb = (size_t)n_nodes * 64 * sizeof(float);
  char* r1 = (char*)d_ws + xb;
  unsigned short* pool_swz = (unsigned short*)r1;
  size_t psz = (size_t)n_gt * 14336 * sizeof(unsigned short);
  unsigned* valid_bits = (unsigned*)(r1 + psz);
  size_t vbsz = (size_t)n_gt * 8 * sizeof(unsigned);
  unsigned short* mfA = (unsigned short*)(r1 + psz + vbsz);
  size_t masz = (size_t)25 * 7 * 512 * sizeof(unsigned short);
  unsigned* mfbits = (unsigned*)(r1 + psz + vbsz + masz);
  size_t mbsz = (size_t)400 * 8 * sizeof(unsigned);
  float* has = (float*)(r1 + psz + vbsz + masz + mbsz);
  float* msg = (float*)(r1 + psz + vbsz + masz + mbsz +
                        ((size_t)n_edges * n_gt * sizeof(float) + 255ul & ~255ul));
  float* gmat = x;  // x region reused after k_pool

  k_prep<<<64, 256, 0, stream>>>(clade_mask, mfA, mfbits, n_edges, n_species);

  int embBlocks = (n_nodes * 16 + 255) / 256;
  k_embed<<<embBlocks, 256, 0, stream>>>(emb, sp_ids, x, n_nodes, n_species);

  for (int l = 0; l < L; ++l) {
    k_msg<<<n_gt, 512, 0, stream>>>(x, msg, src, dst, npg);
    k_mlp2<<<n_nodes / 64, 256, 0, stream>>>(x, msg, W1 + l * 4096, b1 + l * 64,
                                             W2 + l * 4096, b2 + l * 64,
                                             eps + l, lng + l * 64,
                                             lnb + l * 64, x);
  }

  k_pool<<<n_gt, 256, 0, stream>>>(x, sp_ids, leaf_mask, pool_swz, valid_bits,
                                   npg, n_species);
  k_gm2<<<n_gt, 512, 0, stream>>>(pool_swz, valid_bits, mfA, mfbits, gmat, has,
                                  n_edges, n_gt);
  k_stat<<<n_edges, 512, 0, stream>>>(gmat, has, out, n_gt);
}

// Round 8
// 280.537 us; speedup vs baseline: 31.3820x; 1.0689x over previous
//
#include <hip/hip_runtime.h>

// Fixed problem geometry: D=64, n_gt=512, npg=399 nodes/tree, 398 edges/tree.
#define SMAX 200
#define NPG 399

typedef __bf16 bf16x8 __attribute__((ext_vector_type(8)));
typedef _Float16 half8 __attribute__((ext_vector_type(8)));
typedef float f32x4 __attribute__((ext_vector_type(4)));

__device__ __forceinline__ float wredsum(float v) {
  for (int off = 32; off; off >>= 1) v += __shfl_xor(v, off);
  return v;
}
__device__ __forceinline__ unsigned short f2bf(float f) {
  unsigned u = __float_as_uint(f);
  unsigned r = (u + 0x7FFFu + ((u >> 16) & 1u)) >> 16;
  return (unsigned short)r;
}

__global__ __launch_bounds__(256) void k_embed(const float* __restrict__ emb,
                                               const int* __restrict__ sp,
                                               float* __restrict__ x,
                                               int n_nodes, int n_species) {
  int t = blockIdx.x * 256 + threadIdx.x;
  int node = t >> 4, q = t & 15;
  if (node >= n_nodes) return;
  int s = sp[node];
  int row = (s < 0) ? n_species : s;
  reinterpret_cast<float4*>(x)[node * 16 + q] =
      reinterpret_cast<const float4*>(emb)[row * 16 + q];
}

// One block per gene tree. Stage x[tree] (102 KB) in LDS, build the child-CSR
// in LDS (histogram -> Hillis-Steele scan -> scatter), then each wave computes
// msg[i] = sum_children x[c] + x[par[i]] from LDS.
__global__ __launch_bounds__(512) void k_msg(const float* __restrict__ x,
                                             float* __restrict__ msg,
                                             const int* __restrict__ src,
                                             const int* __restrict__ dst,
                                             int npg) {
  __shared__ __attribute__((aligned(16))) float sX[NPG * 64];
  __shared__ int sStart[NPG + 1];
  __shared__ int sChild[NPG - 1];
  __shared__ int sPar[NPG];
  __shared__ int sCnt[NPG];
  int g = blockIdx.x;
  int tid = threadIdx.x;
  int nEt = npg - 1;
  int base = g * npg;
  int ebase = g * nEt;
  for (int i = tid; i < npg + 1; i += 512) sStart[i] = 0;
  for (int i = tid; i < npg; i += 512) sCnt[i] = 0;
  __syncthreads();
  const float4* xg4 = reinterpret_cast<const float4*>(x + (size_t)base * 64);
  for (int i = tid; i < npg * 16; i += 512)
    reinterpret_cast<float4*>(sX)[i] = xg4[i];
  for (int i = tid; i < nEt; i += 512) {
    int c = src[ebase + i] - base;
    int p = dst[ebase + i] - base;
    sPar[c] = p;
    atomicAdd(&sStart[p + 1], 1);
  }
  __syncthreads();
  for (int off = 1; off < npg + 1; off <<= 1) {
    int t = 0;
    if (tid < npg + 1 && tid >= off) t = sStart[tid - off];
    __syncthreads();
    if (tid < npg + 1 && tid >= off) sStart[tid] += t;
    __syncthreads();
  }
  for (int c = tid + 1; c < npg; c += 512) {
    int p = sPar[c];
    int pos = sStart[p] + atomicAdd(&sCnt[p], 1);
    sChild[pos] = c;
  }
  __syncthreads();
  int w = tid >> 6, lane = tid & 63;
  for (int i = w; i < npg; i += 8) {
    float s = 0.f;
    int j0 = sStart[i], j1 = sStart[i + 1];
    for (int j = j0; j < j1; ++j) s += sX[sChild[j] * 64 + lane];
    if (i > 0) s += sX[sPar[i] * 64 + lane];
    msg[(size_t)(base + i) * 64 + lane] = s;
  }
}

// MFMA MLP: 256 threads = 4 waves x 16 nodes. u=(1+eps)x+msg cast to f16,
// W1/W2 fragment-swizzled f16 in LDS; MFMA 16x16x32_f16; relu+bias between;
// residual + LayerNorm in f32. Fragment maps HW-verified by k_gm2.
__global__ __launch_bounds__(256) void k_mlp2(const float* __restrict__ x_io,
                                              const float* __restrict__ msg,
                                              const float* __restrict__ W1,
                                              const float* __restrict__ b1,
                                              const float* __restrict__ W2,
                                              const float* __restrict__ b2,
                                              const float* __restrict__ eps_p,
                                              const float* __restrict__ gam,
                                              const float* __restrict__ bet,
                                              float* __restrict__ x_out) {
  __shared__ __attribute__((aligned(16))) _Float16 sWf[2][4096];
  __shared__ __attribute__((aligned(16))) float sXt[4][16 * 72];
  __shared__ __attribute__((aligned(16))) float sUt[4][16 * 72];
  int tid = threadIdx.x;
  for (int idx = tid; idx < 4096; idx += 256) {
    int k = idx >> 6, n = idx & 63;
    int frag = (k >> 5) * 4 + (n >> 4);
    int ln = ((k >> 3) & 3) * 16 + (n & 15);
    int j = k & 7;
    sWf[0][frag * 512 + ln * 8 + j] = (_Float16)W1[idx];
    sWf[1][frag * 512 + ln * 8 + j] = (_Float16)W2[idx];
  }
  __syncthreads();
  int w = tid >> 6, lane = tid & 63;
  int g = lane >> 4, c = lane & 15;
  float e1 = 1.0f + eps_p[0];
  int tb = blockIdx.x * 64 + w * 16;
  float b1v[4], b2v[4], gv[4], bv[4];
#pragma unroll
  for (int nt = 0; nt < 4; ++nt) {
    b1v[nt] = b1[c + 16 * nt];
    b2v[nt] = b2[c + 16 * nt];
    gv[nt] = gam[c + 16 * nt];
    bv[nt] = bet[c + 16 * nt];
  }
  float* xt = sXt[w];
  float* ut = sUt[w];
#pragma unroll
  for (int it = 0; it < 4; ++it) {
    int m = it * 4 + g;
    float4 xv = reinterpret_cast<const float4*>(x_io)[(size_t)(tb + m) * 16 + c];
    float4 mv = reinterpret_cast<const float4*>(msg)[(size_t)(tb + m) * 16 + c];
    float4 uv;
    uv.x = fmaf(e1, xv.x, mv.x);
    uv.y = fmaf(e1, xv.y, mv.y);
    uv.z = fmaf(e1, xv.z, mv.z);
    uv.w = fmaf(e1, xv.w, mv.w);
    *reinterpret_cast<float4*>(&xt[m * 72 + c * 4]) = xv;
    *reinterpret_cast<float4*>(&ut[m * 72 + c * 4]) = uv;
  }
  // ---- matvec 1: t = relu(u @ W1 + b1) ----
  half8 a1[2];
#pragma unroll
  for (int kt = 0; kt < 2; ++kt) {
    int k0 = kt * 32 + g * 8;
    float4 p0 = *reinterpret_cast<const float4*>(&ut[c * 72 + k0]);
    float4 p1 = *reinterpret_cast<const float4*>(&ut[c * 72 + k0 + 4]);
    half8 a;
    a[0] = (_Float16)p0.x; a[1] = (_Float16)p0.y;
    a[2] = (_Float16)p0.z; a[3] = (_Float16)p0.w;
    a[4] = (_Float16)p1.x; a[5] = (_Float16)p1.y;
    a[6] = (_Float16)p1.z; a[7] = (_Float16)p1.w;
    a1[kt] = a;
  }
  const half8* B1 = reinterpret_cast<const half8*>(sWf[0]);
  f32x4 tacc[4];
#pragma unroll
  for (int nt = 0; nt < 4; ++nt) tacc[nt] = (f32x4){0.f, 0.f, 0.f, 0.f};
#pragma unroll
  for (int kt = 0; kt < 2; ++kt)
#pragma unroll
    for (int nt = 0; nt < 4; ++nt)
      tacc[nt] = __builtin_amdgcn_mfma_f32_16x16x32_f16(
          a1[kt], B1[(kt * 4 + nt) * 64 + lane], tacc[nt], 0, 0, 0);
#pragma unroll
  for (int nt = 0; nt < 4; ++nt)
#pragma unroll
    for (int r = 0; r < 4; ++r)
      ut[(g * 4 + r) * 72 + c + 16 * nt] = fmaxf(tacc[nt][r] + b1v[nt], 0.f);
  // ---- matvec 2: h = t @ W2 + b2 ----
  half8 a2[2];
#pragma unroll
  for (int kt = 0; kt < 2; ++kt) {
    int k0 = kt * 32 + g * 8;
    float4 p0 = *reinterpret_cast<const float4*>(&ut[c * 72 + k0]);
    float4 p1 = *reinterpret_cast<const float4*>(&ut[c * 72 + k0 + 4]);
    half8 a;
    a[0] = (_Float16)p0.x; a[1] = (_Float16)p0.y;
    a[2] = (_Float16)p0.z; a[3] = (_Float16)p0.w;
    a[4] = (_Float16)p1.x; a[5] = (_Float16)p1.y;
    a[6] = (_Float16)p1.z; a[7] = (_Float16)p1.w;
    a2[kt] = a;
  }
  const half8* B2 = reinterpret_cast<const half8*>(sWf[1]);
  f32x4 hacc[4];
#pragma unroll
  for (int nt = 0; nt < 4; ++nt) hacc[nt] = (f32x4){0.f, 0.f, 0.f, 0.f};
#pragma unroll
  for (int kt = 0; kt < 2; ++kt)
#pragma unroll
    for (int nt = 0; nt < 4; ++nt)
      hacc[nt] = __builtin_amdgcn_mfma_f32_16x16x32_f16(
          a2[kt], B2[(kt * 4 + nt) * 64 + lane], hacc[nt], 0, 0, 0);
  // ---- residual + LayerNorm (f32) ----
  float y[4][4];  // [r][nt]
#pragma unroll
  for (int r = 0; r < 4; ++r)
#pragma unroll
    for (int nt = 0; nt < 4; ++nt)
      y[r][nt] = xt[(g * 4 + r) * 72 + c + 16 * nt] + hacc[nt][r] + b2v[nt];
  float mu[4], iv[4];
#pragma unroll
  for (int r = 0; r < 4; ++r) {
    float s = y[r][0] + y[r][1] + y[r][2] + y[r][3];
    s += __shfl_xor(s, 1);
    s += __shfl_xor(s, 2);
    s += __shfl_xor(s, 4);
    s += __shfl_xor(s, 8);
    mu[r] = s * (1.f / 64.f);
    float d0 = y[r][0] - mu[r], d1 = y[r][1] - mu[r];
    float d2 = y[r][2] - mu[r], d3 = y[r][3] - mu[r];
    float v = d0 * d0 + d1 * d1 + d2 * d2 + d3 * d3;
    v += __shfl_xor(v, 1);
    v += __shfl_xor(v, 2);
    v += __shfl_xor(v, 4);
    v += __shfl_xor(v, 8);
    iv[r] = rsqrtf(v * (1.f / 64.f) + 1e-5f);
  }
#pragma unroll
  for (int r = 0; r < 4; ++r)
#pragma unroll
    for (int nt = 0; nt < 4; ++nt)
      x_out[(size_t)(tb + g * 4 + r) * 64 + c + 16 * nt] =
          (y[r][nt] - mu[r]) * iv[r] * gv[nt] + bv[nt];
}

// Build A-operand fragments (mf as bf16, pre-swizzled into the 16x16x32 MFMA
// lane layout) and packed mf bitmasks.
__global__ __launch_bounds__(256) void k_prep(const int* __restrict__ clade,
                                              unsigned short* __restrict__ mfA,
                                              unsigned* __restrict__ mfbits,
                                              int n_edges, int n_species) {
  int stride = gridDim.x * 256;
  for (int idx = blockIdx.x * 256 + threadIdx.x; idx < 25 * 7 * 512;
       idx += stride) {
    int fi = idx >> 9, within = idx & 511;
    int mt = fi / 7, kt = fi % 7;
    int l = within >> 3, j = within & 7;
    int e = mt * 16 + (l & 15);
    int s = kt * 32 + ((l >> 4) & 3) * 8 + j;
    unsigned short v = 0;
    if (e < n_edges && s < n_species && clade[(size_t)e * n_species + s] != 0)
      v = 0x3F80;  // bf16(1.0)
    mfA[idx] = v;
  }
  for (int idx = blockIdx.x * 256 + threadIdx.x; idx < 400 * 8; idx += stride) {
    int e = idx >> 3, w = idx & 7;
    unsigned bits = 0;
    if (e < n_edges && w < 7) {
      for (int b = 0; b < 32; ++b) {
        int s = w * 32 + b;
        if (s < n_species && clade[(size_t)e * n_species + s] != 0)
          bits |= 1u << b;
      }
    }
    mfbits[idx] = bits;
  }
}

// Species pooling v2: 8 waves/block (2 blocks/CU), sp/leaf predicated into an
// LDS table first, 4 nodes per wave-iteration via float4 lanes, LDS atomics,
// vectorized (uint4 = 8 bf16) fragment-swizzled epilogue.
__global__ __launch_bounds__(512) void k_pool(const float* __restrict__ x,
                                              const int* __restrict__ sp,
                                              const int* __restrict__ leaf,
                                              unsigned short* __restrict__ pool_swz,
                                              unsigned* __restrict__ valid_bits,
                                              int npg, int n_species) {
  __shared__ __attribute__((aligned(16))) float acc[200 * 64];
  __shared__ float cnt[200];
  __shared__ int ssp[NPG];
  int g = blockIdx.x;
  int tid = threadIdx.x;
  for (int i = tid; i < n_species * 64; i += 512) acc[i] = 0.f;
  for (int i = tid; i < n_species; i += 512) cnt[i] = 0.f;
  for (int i = tid; i < npg; i += 512) {
    int node = g * npg + i;
    int s = sp[node];
    ssp[i] = (s >= 0 && leaf[node]) ? s : -1;
  }
  __syncthreads();
  int w = tid >> 6, lane = tid & 63;
  int n4 = lane >> 4, dq = lane & 15;
  const float4* x4 = reinterpret_cast<const float4*>(x);
  for (int i0 = w * 4; i0 < npg; i0 += 32) {
    int i = i0 + n4;
    int s = (i < npg) ? ssp[i] : -1;
    if (s >= 0) {
      float4 v = x4[((size_t)g * npg + i) * 16 + dq];
      atomicAdd(&acc[s * 64 + dq * 4 + 0], v.x);
      atomicAdd(&acc[s * 64 + dq * 4 + 1], v.y);
      atomicAdd(&acc[s * 64 + dq * 4 + 2], v.z);
      atomicAdd(&acc[s * 64 + dq * 4 + 3], v.w);
      if (dq == 0) atomicAdd(&cnt[s], 1.f);
    }
  }
  __syncthreads();
  if (tid < 8) {
    unsigned bits = 0;
    if (tid < 7) {
      for (int b = 0; b < 32; ++b) {
        int s = tid * 32 + b;
        if (s < n_species && cnt[s] > 0.f) bits |= 1u << b;
      }
    }
    valid_bits[(size_t)g * 8 + tid] = bits;
  }
  // epilogue: idx -> (frag, ln); 8 consecutive s at fixed d -> one uint4 store
  unsigned short* pg = pool_swz + (size_t)g * 14336;
  for (int idx = tid; idx < 1792; idx += 512) {
    int frag = idx >> 6, ln = idx & 63;
    int sbase = (frag >> 2) * 32 + (ln >> 4) * 8;
    int d = (frag & 3) * 16 + (ln & 15);
    unsigned pk[4];
#pragma unroll
    for (int jp = 0; jp < 4; ++jp) {
      int s0 = sbase + jp * 2, s1 = s0 + 1;
      float v0 = (s0 < n_species) ? acc[s0 * 64 + d] / fmaxf(cnt[s0], 1.f) : 0.f;
      float v1 = (s1 < n_species) ? acc[s1 * 64 + d] / fmaxf(cnt[s1], 1.f) : 0.f;
      pk[jp] = (unsigned)f2bf(v0) | ((unsigned)f2bf(v1) << 16);
    }
    uint4 u = {pk[0], pk[1], pk[2], pk[3]};
    *reinterpret_cast<uint4*>(&pg[idx * 8]) = u;
  }
}

// MFMA clade-sum: one WG per gene tree g.
__global__ __launch_bounds__(512) void k_gm2(const unsigned short* __restrict__ pool_swz,
                                             const unsigned* __restrict__ valid_bits,
                                             const unsigned short* __restrict__ mfA,
                                             const unsigned* __restrict__ mfbits,
                                             float* __restrict__ gmat,
                                             float* __restrict__ has,
                                             int n_edges, int n_gt) {
  __shared__ __attribute__((aligned(16))) unsigned short sBf[14336];
  __shared__ float sInv[400];
  __shared__ float sHas[400];
  int g = blockIdx.x;
  int tid = threadIdx.x;
  const float4* src4 =
      reinterpret_cast<const float4*>(pool_swz + (size_t)g * 14336);
  float4* dst4 = reinterpret_cast<float4*>(sBf);
  for (int i = tid; i < 1792; i += 512) dst4[i] = src4[i];
  unsigned vb[7];
#pragma unroll
  for (int w2 = 0; w2 < 7; ++w2) vb[w2] = valid_bits[(size_t)g * 8 + w2];
  for (int e = tid; e < 400; e += 512) {
    unsigned cc = 0;
#pragma unroll
    for (int w2 = 0; w2 < 7; ++w2) cc += __popc(mfbits[e * 8 + w2] & vb[w2]);
    sInv[e] = 1.f / (float)max(cc, 1u);
    sHas[e] = (cc > 0) ? 1.f : 0.f;
  }
  __syncthreads();
  int w = tid >> 6, lane = tid & 63;
  const bf16x8* A = reinterpret_cast<const bf16x8*>(mfA);
  const bf16x8* Bb = reinterpret_cast<const bf16x8*>(sBf);
  for (int mt = w; mt < 25; mt += 8) {
    bf16x8 af[7];
#pragma unroll
    for (int kt = 0; kt < 7; ++kt) af[kt] = A[(mt * 7 + kt) * 64 + lane];
    f32x4 acc0 = {0.f, 0.f, 0.f, 0.f};
    f32x4 acc1 = {0.f, 0.f, 0.f, 0.f};
    f32x4 acc2 = {0.f, 0.f, 0.f, 0.f};
    f32x4 acc3 = {0.f, 0.f, 0.f, 0.f};
#pragma unroll
    for (int kt = 0; kt < 7; ++kt) {
      const bf16x8* B = Bb + kt * 256 + lane;
      acc0 = __builtin_amdgcn_mfma_f32_16x16x32_bf16(af[kt], B[0], acc0, 0, 0, 0);
      acc1 = __builtin_amdgcn_mfma_f32_16x16x32_bf16(af[kt], B[64], acc1, 0, 0, 0);
      acc2 = __builtin_amdgcn_mfma_f32_16x16x32_bf16(af[kt], B[128], acc2, 0, 0, 0);
      acc3 = __builtin_amdgcn_mfma_f32_16x16x32_bf16(af[kt], B[192], acc3, 0, 0, 0);
    }
    int rbase = mt * 16 + (lane >> 4) * 4;
    int col = lane & 15;
#pragma unroll
    for (int r = 0; r < 4; ++r) {
      int e = rbase + r;
      if (e >= n_edges) continue;
      float inv = sInv[e];
      float* gp = gmat + ((size_t)e * n_gt + g) * 64 + col;
      gp[0] = acc0[r] * inv;
      gp[16] = acc1[r] * inv;
      gp[32] = acc2[r] * inv;
      gp[48] = acc3[r] * inv;
      if (col == 0) has[(size_t)e * n_gt + g] = sHas[e];
    }
  }
}

// One block per species-tree edge: streaming mean/std over gene trees.
__global__ __launch_bounds__(512) void k_stat(const float* __restrict__ gmat,
                                              const float* __restrict__ has,
                                              float* __restrict__ out,
                                              int n_gt) {
  __shared__ float red1[8][64];
  __shared__ float red2[8][64];
  __shared__ float redn[8];
  int e = blockIdx.x;
  int tid = threadIdx.x, w = tid >> 6, lane = tid & 63;
  const float* ge = gmat + (size_t)e * n_gt * 64;
  const float* he = has + (size_t)e * n_gt;
  float S1 = 0.f, S2 = 0.f, nv = 0.f;
  for (int g = w; g < n_gt; g += 8) {
    float h = he[g];
    float v = ge[g * 64 + lane];
    S1 += h * v;
    S2 += h * v * v;
    nv += h;
  }
  red1[w][lane] = S1;
  red2[w][lane] = S2;
  if (lane == 0) redn[w] = nv;
  __syncthreads();
  if (w == 0) {
    float s1 = 0.f, s2 = 0.f, n_v = 0.f;
#pragma unroll
    for (int j = 0; j < 8; ++j) {
      s1 += red1[j][lane];
      s2 += red2[j][lane];
      n_v += redn[j];
    }
    float mean = s1 / fmaxf(n_v, 1.f);
    float var = (s2 - s1 * s1 / fmaxf(n_v, 1.f)) / fmaxf(n_v - 1.f, 1.f);
    float stdv = (n_v > 1.f) ? sqrtf(fmaxf(var, 0.f)) : 0.f;
    out[(size_t)e * 128 + lane] = (n_v > 0.f) ? mean : 0.f;
    out[(size_t)e * 128 + 64 + lane] = stdv;
  }
}

extern "C" void kernel_launch(void* const* d_in, const int* in_sizes, int n_in,
                              void* d_out, int out_size, void* d_ws, size_t ws_size,
                              hipStream_t stream) {
  (void)n_in; (void)out_size; (void)ws_size;
  const int* edge_index = (const int*)d_in[0];
  const int* sp_ids = (const int*)d_in[1];
  const int* leaf_mask = (const int*)d_in[2];
  const int* clade_mask = (const int*)d_in[4];
  const float* emb = (const float*)d_in[6];
  const float* W1 = (const float*)d_in[7];
  const float* b1 = (const float*)d_in[8];
  const float* W2 = (const float*)d_in[9];
  const float* b2 = (const float*)d_in[10];
  const float* eps = (const float*)d_in[11];
  const float* lng = (const float*)d_in[12];
  const float* lnb = (const float*)d_in[13];
  float* out = (float*)d_out;

  const int n_nodes = in_sizes[1];             // 204288
  const int nE = in_sizes[0] / 2;              // 407552 directed edges
  const int n_species = in_sizes[6] / 64 - 1;  // 200
  const int n_edges = in_sizes[4] / n_species; // 397
  const int L = in_sizes[11];                  // 2
  const int n_gt = 512;                        // fixed problem size
  const int npg = n_nodes / n_gt;              // 399 nodes per gene tree

  const int* src = edge_index;       // first half: child ids
  const int* dst = edge_index + nE;  // first half: parent ids

  float* x = (float*)d_ws;
  size_t xb = (size_t)n_nodes * 64 * sizeof(float);
  char* r1 = (char*)d_ws + xb;
  unsigned short* pool_swz = (unsigned short*)r1;
  size_t psz = (size_t)n_gt * 14336 * sizeof(unsigned short);
  unsigned* valid_bits = (unsigned*)(r1 + psz);
  size_t vbsz = (size_t)n_gt * 8 * sizeof(unsigned);
  unsigned short* mfA = (unsigned short*)(r1 + psz + vbsz);
  size_t masz = (size_t)25 * 7 * 512 * sizeof(unsigned short);
  unsigned* mfbits = (unsigned*)(r1 + psz + vbsz + masz);
  size_t mbsz = (size_t)400 * 8 * sizeof(unsigned);
  float* has = (float*)(r1 + psz + vbsz + masz + mbsz);
  float* msg = (float*)(r1 + psz + vbsz + masz + mbsz +
                        ((size_t)n_edges * n_gt * sizeof(float) + 255ul & ~255ul));
  float* gmat = x;  // x region reused after k_pool

  k_prep<<<64, 256, 0, stream>>>(clade_mask, mfA, mfbits, n_edges, n_species);

  int embBlocks = (n_nodes * 16 + 255) / 256;
  k_embed<<<embBlocks, 256, 0, stream>>>(emb, sp_ids, x, n_nodes, n_species);

  for (int l = 0; l < L; ++l) {
    k_msg<<<n_gt, 512, 0, stream>>>(x, msg, src, dst, npg);
    k_mlp2<<<n_nodes / 64, 256, 0, stream>>>(x, msg, W1 + l * 4096, b1 + l * 64,
                                             W2 + l * 4096, b2 + l * 64,
                                             eps + l, lng + l * 64,
                                             lnb + l * 64, x);
  }

  k_pool<<<n_gt, 512, 0, stream>>>(x, sp_ids, leaf_mask, pool_swz, valid_bits,
                                   npg, n_species);
  k_gm2<<<n_gt, 512, 0, stream>>>(pool_swz, valid_bits, mfA, mfbits, gmat, has,
                                  n_edges, n_gt);
  k_stat<<<n_edges, 512, 0, stream>>>(gmat, has, out, n_gt);
}

// Round 9
// 220.278 us; speedup vs baseline: 39.9667x; 1.2736x over previous
//
#include <hip/hip_runtime.h>

// Fixed problem geometry: D=64, n_gt=512, npg=399 nodes/tree, 398 edges/tree.
#define SMAX 200
#define NPG 399

typedef __bf16 bf16x8 __attribute__((ext_vector_type(8)));
typedef _Float16 half8 __attribute__((ext_vector_type(8)));
typedef float f32x4 __attribute__((ext_vector_type(4)));

__device__ __forceinline__ unsigned short f2bf(float f) {
  unsigned u = __float_as_uint(f);
  unsigned r = (u + 0x7FFFu + ((u >> 16) & 1u)) >> 16;
  return (unsigned short)r;
}

// Fused GIN layer: one block per gene tree, 8 waves.
//  phase 1: stage x (f32, LDS) [layer0: gather emb], W1/W2 (f16 frag-swizzled),
//           build child-CSR in LDS (hist -> scan -> scatter).
//  phase 2 (no cross-wave deps): each wave owns tiles of 16 nodes:
//           msg+u from sX -> XOR-swizzled f16 tile buf -> MFMA1 -> relu ->
//           MFMA2 -> residual+LN (f32) -> global write.
// Fragment maps HW-verified by k_gm2/k_mlp2 (rounds 6-7).
__global__ __launch_bounds__(512) void k_layer(
    const float* __restrict__ x_in, const float* __restrict__ emb,
    const int* __restrict__ sp, const int* __restrict__ src,
    const int* __restrict__ dst, const float* __restrict__ W1,
    const float* __restrict__ b1, const float* __restrict__ W2,
    const float* __restrict__ b2, const float* __restrict__ eps_p,
    const float* __restrict__ gam, const float* __restrict__ bet,
    float* __restrict__ x_out, int npg, int n_species, int layer0) {
  __shared__ __attribute__((aligned(16))) float sX[NPG * 64];
  __shared__ __attribute__((aligned(16))) _Float16 sT[8][1024];
  __shared__ __attribute__((aligned(16))) _Float16 sWf[2][4096];
  __shared__ int sStart[NPG + 1];
  __shared__ int sChild[NPG - 1];
  __shared__ int sPar[NPG];
  __shared__ int sCnt[NPG];
  int g = blockIdx.x, tid = threadIdx.x;
  int base = g * npg, nEt = npg - 1, ebase = g * nEt;
  for (int i = tid; i < npg + 1; i += 512) sStart[i] = 0;
  for (int i = tid; i < npg; i += 512) sCnt[i] = 0;
  __syncthreads();
  for (int idx = tid; idx < 4096; idx += 512) {
    int k = idx >> 6, n = idx & 63;
    int frag = (k >> 5) * 4 + (n >> 4);
    int ln = ((k >> 3) & 3) * 16 + (n & 15);
    int j = k & 7;
    sWf[0][frag * 512 + ln * 8 + j] = (_Float16)W1[idx];
    sWf[1][frag * 512 + ln * 8 + j] = (_Float16)W2[idx];
  }
  if (layer0) {
    for (int idx = tid; idx < npg * 16; idx += 512) {
      int node = idx >> 4, q = idx & 15;
      int s = sp[base + node];
      int row = (s < 0) ? n_species : s;
      float4 v = reinterpret_cast<const float4*>(emb)[row * 16 + q];
      *reinterpret_cast<float4*>(&sX[node * 64 + q * 4]) = v;
    }
  } else {
    const float4* xg4 =
        reinterpret_cast<const float4*>(x_in + (size_t)base * 64);
    for (int i = tid; i < npg * 16; i += 512)
      reinterpret_cast<float4*>(sX)[i] = xg4[i];
  }
  for (int i = tid; i < nEt; i += 512) {
    int c = src[ebase + i] - base;
    int p = dst[ebase + i] - base;
    sPar[c] = p;
    atomicAdd(&sStart[p + 1], 1);
  }
  __syncthreads();
  for (int off = 1; off < npg + 1; off <<= 1) {
    int t = 0;
    if (tid < npg + 1 && tid >= off) t = sStart[tid - off];
    __syncthreads();
    if (tid < npg + 1 && tid >= off) sStart[tid] += t;
    __syncthreads();
  }
  for (int c = tid + 1; c < npg; c += 512) {
    int p = sPar[c];
    int pos = sStart[p] + atomicAdd(&sCnt[p], 1);
    sChild[pos] = c;
  }
  __syncthreads();
  int w = tid >> 6, lane = tid & 63;
  int cc = lane & 15, gq = lane >> 4;
  float e1 = 1.0f + eps_p[0];
  float b1v[4], b2v[4], gv[4], bv[4];
#pragma unroll
  for (int nt = 0; nt < 4; ++nt) {
    b1v[nt] = b1[cc + 16 * nt];
    b2v[nt] = b2[cc + 16 * nt];
    gv[nt] = gam[cc + 16 * nt];
    bv[nt] = bet[cc + 16 * nt];
  }
  _Float16* tb = sT[w];
  const half8* B1 = reinterpret_cast<const half8*>(sWf[0]);
  const half8* B2 = reinterpret_cast<const half8*>(sWf[1]);
  int ntiles = (npg + 15) >> 4;
  for (int t = w; t < ntiles; t += 8) {
    int n0 = t * 16;
    // msg + u -> tile buffer (XOR-swizzled, k ^= (m&7)<<3)
#pragma unroll 4
    for (int mm = 0; mm < 16; ++mm) {
      int node = n0 + mm;
      float u = 0.f;
      if (node < npg) {
        float s = 0.f;
        int j0 = sStart[node], j1 = sStart[node + 1];
        for (int j = j0; j < j1; ++j) s += sX[sChild[j] * 64 + lane];
        if (node > 0) s += sX[sPar[node] * 64 + lane];
        u = fmaf(e1, sX[node * 64 + lane], s);
      }
      tb[mm * 64 + (lane ^ ((mm & 7) << 3))] = (_Float16)u;
    }
    int sw = (cc & 7) << 3;
    half8 a1_0 = *reinterpret_cast<const half8*>(&tb[cc * 64 + ((gq * 8) ^ sw)]);
    half8 a1_1 =
        *reinterpret_cast<const half8*>(&tb[cc * 64 + ((32 + gq * 8) ^ sw)]);
    f32x4 tacc[4];
#pragma unroll
    for (int nt = 0; nt < 4; ++nt) tacc[nt] = (f32x4){0.f, 0.f, 0.f, 0.f};
#pragma unroll
    for (int nt = 0; nt < 4; ++nt) {
      tacc[nt] = __builtin_amdgcn_mfma_f32_16x16x32_f16(
          a1_0, B1[nt * 64 + lane], tacc[nt], 0, 0, 0);
      tacc[nt] = __builtin_amdgcn_mfma_f32_16x16x32_f16(
          a1_1, B1[(4 + nt) * 64 + lane], tacc[nt], 0, 0, 0);
    }
#pragma unroll
    for (int nt = 0; nt < 4; ++nt)
#pragma unroll
      for (int r = 0; r < 4; ++r) {
        int m = gq * 4 + r;
        tb[m * 64 + ((cc + 16 * nt) ^ ((m & 7) << 3))] =
            (_Float16)fmaxf(tacc[nt][r] + b1v[nt], 0.f);
      }
    half8 a2_0 = *reinterpret_cast<const half8*>(&tb[cc * 64 + ((gq * 8) ^ sw)]);
    half8 a2_1 =
        *reinterpret_cast<const half8*>(&tb[cc * 64 + ((32 + gq * 8) ^ sw)]);
    f32x4 hacc[4];
#pragma unroll
    for (int nt = 0; nt < 4; ++nt) hacc[nt] = (f32x4){0.f, 0.f, 0.f, 0.f};
#pragma unroll
    for (int nt = 0; nt < 4; ++nt) {
      hacc[nt] = __builtin_amdgcn_mfma_f32_16x16x32_f16(
          a2_0, B2[nt * 64 + lane], hacc[nt], 0, 0, 0);
      hacc[nt] = __builtin_amdgcn_mfma_f32_16x16x32_f16(
          a2_1, B2[(4 + nt) * 64 + lane], hacc[nt], 0, 0, 0);
    }
    // residual + LayerNorm (f32)
    float y[4][4];
#pragma unroll
    for (int r = 0; r < 4; ++r) {
      int node = n0 + gq * 4 + r;
#pragma unroll
      for (int nt = 0; nt < 4; ++nt)
        y[r][nt] = ((node < npg) ? sX[node * 64 + cc + 16 * nt] : 0.f) +
                   hacc[nt][r] + b2v[nt];
    }
#pragma unroll
    for (int r = 0; r < 4; ++r) {
      float s = y[r][0] + y[r][1] + y[r][2] + y[r][3];
      s += __shfl_xor(s, 1);
      s += __shfl_xor(s, 2);
      s += __shfl_xor(s, 4);
      s += __shfl_xor(s, 8);
      float mu = s * (1.f / 64.f);
      float d0 = y[r][0] - mu, d1 = y[r][1] - mu;
      float d2 = y[r][2] - mu, d3 = y[r][3] - mu;
      float v = d0 * d0 + d1 * d1 + d2 * d2 + d3 * d3;
      v += __shfl_xor(v, 1);
      v += __shfl_xor(v, 2);
      v += __shfl_xor(v, 4);
      v += __shfl_xor(v, 8);
      float iv = rsqrtf(v * (1.f / 64.f) + 1e-5f);
      int node = n0 + gq * 4 + r;
      if (node < npg) {
#pragma unroll
        for (int nt = 0; nt < 4; ++nt)
          x_out[(size_t)(base + node) * 64 + cc + 16 * nt] =
              (y[r][nt] - mu) * iv * gv[nt] + bv[nt];
      }
    }
  }
}

// Build A-operand fragments (mf as bf16, pre-swizzled into the 16x16x32 MFMA
// lane layout) and packed mf bitmasks.
__global__ __launch_bounds__(256) void k_prep(const int* __restrict__ clade,
                                              unsigned short* __restrict__ mfA,
                                              unsigned* __restrict__ mfbits,
                                              int n_edges, int n_species) {
  int stride = gridDim.x * 256;
  for (int idx = blockIdx.x * 256 + threadIdx.x; idx < 25 * 7 * 512;
       idx += stride) {
    int fi = idx >> 9, within = idx & 511;
    int mt = fi / 7, kt = fi % 7;
    int l = within >> 3, j = within & 7;
    int e = mt * 16 + (l & 15);
    int s = kt * 32 + ((l >> 4) & 3) * 8 + j;
    unsigned short v = 0;
    if (e < n_edges && s < n_species && clade[(size_t)e * n_species + s] != 0)
      v = 0x3F80;  // bf16(1.0)
    mfA[idx] = v;
  }
  for (int idx = blockIdx.x * 256 + threadIdx.x; idx < 400 * 8; idx += stride) {
    int e = idx >> 3, w = idx & 7;
    unsigned bits = 0;
    if (e < n_edges && w < 7) {
      for (int b = 0; b < 32; ++b) {
        int s = w * 32 + b;
        if (s < n_species && clade[(size_t)e * n_species + s] != 0)
          bits |= 1u << b;
      }
    }
    mfbits[idx] = bits;
  }
}

// Species pooling v3: block per tree; per-species node lists built in LDS
// (hist -> scan -> scatter); each wave owns whole species rows (lane = dim),
// no data atomics; vectorized fragment-swizzled bf16 epilogue.
__global__ __launch_bounds__(512) void k_pool(const float* __restrict__ x,
                                              const int* __restrict__ sp,
                                              const int* __restrict__ leaf,
                                              unsigned short* __restrict__ pool_swz,
                                              unsigned* __restrict__ valid_bits,
                                              int npg, int n_species) {
  __shared__ __attribute__((aligned(16))) float acc[SMAX * 64];
  __shared__ float cntf[SMAX];
  __shared__ int spStart[SMAX + 1];
  __shared__ int spNode[NPG];
  __shared__ int spCur[SMAX];
  __shared__ int sSp[NPG];
  int g = blockIdx.x, tid = threadIdx.x;
  for (int i = tid; i < n_species + 1; i += 512) spStart[i] = 0;
  for (int i = tid; i < n_species; i += 512) spCur[i] = 0;
  __syncthreads();
  for (int i = tid; i < npg; i += 512) {
    int node = g * npg + i;
    int s = sp[node];
    bool v = (s >= 0) && leaf[node];
    sSp[i] = v ? s : -1;
    if (v) atomicAdd(&spStart[s + 1], 1);
  }
  __syncthreads();
  for (int off = 1; off < n_species + 1; off <<= 1) {
    int t = 0;
    if (tid < n_species + 1 && tid >= off) t = spStart[tid - off];
    __syncthreads();
    if (tid < n_species + 1 && tid >= off) spStart[tid] += t;
    __syncthreads();
  }
  for (int i = tid; i < npg; i += 512) {
    int s = sSp[i];
    if (s >= 0) {
      int pos = spStart[s] + atomicAdd(&spCur[s], 1);
      spNode[pos] = i;
    }
  }
  __syncthreads();
  int w = tid >> 6, lane = tid & 63;
  for (int s = w; s < n_species; s += 8) {
    int j0 = spStart[s], j1 = spStart[s + 1];
    float sum = 0.f;
    for (int j = j0; j < j1; ++j)
      sum += x[((size_t)g * npg + spNode[j]) * 64 + lane];
    acc[s * 64 + lane] = sum;
    if (lane == 0) cntf[s] = (float)(j1 - j0);
  }
  __syncthreads();
  if (tid < 8) {
    unsigned bits = 0;
    if (tid < 7) {
      for (int b = 0; b < 32; ++b) {
        int s = tid * 32 + b;
        if (s < n_species && cntf[s] > 0.f) bits |= 1u << b;
      }
    }
    valid_bits[(size_t)g * 8 + tid] = bits;
  }
  unsigned short* pg = pool_swz + (size_t)g * 14336;
  for (int idx = tid; idx < 1792; idx += 512) {
    int frag = idx >> 6, ln = idx & 63;
    int sbase = (frag >> 2) * 32 + (ln >> 4) * 8;
    int d = (frag & 3) * 16 + (ln & 15);
    unsigned pk[4];
#pragma unroll
    for (int jp = 0; jp < 4; ++jp) {
      int s0 = sbase + jp * 2, s1 = s0 + 1;
      float v0 =
          (s0 < n_species) ? acc[s0 * 64 + d] / fmaxf(cntf[s0], 1.f) : 0.f;
      float v1 =
          (s1 < n_species) ? acc[s1 * 64 + d] / fmaxf(cntf[s1], 1.f) : 0.f;
      pk[jp] = (unsigned)f2bf(v0) | ((unsigned)f2bf(v1) << 16);
    }
    uint4 u = {pk[0], pk[1], pk[2], pk[3]};
    *reinterpret_cast<uint4*>(&pg[idx * 8]) = u;
  }
}

// MFMA clade-sum: one WG per gene tree g.
__global__ __launch_bounds__(512) void k_gm2(const unsigned short* __restrict__ pool_swz,
                                             const unsigned* __restrict__ valid_bits,
                                             const unsigned short* __restrict__ mfA,
                                             const unsigned* __restrict__ mfbits,
                                             float* __restrict__ gmat,
                                             float* __restrict__ has,
                                             int n_edges, int n_gt) {
  __shared__ __attribute__((aligned(16))) unsigned short sBf[14336];
  __shared__ float sInv[400];
  __shared__ float sHas[400];
  int g = blockIdx.x;
  int tid = threadIdx.x;
  const float4* src4 =
      reinterpret_cast<const float4*>(pool_swz + (size_t)g * 14336);
  float4* dst4 = reinterpret_cast<float4*>(sBf);
  for (int i = tid; i < 1792; i += 512) dst4[i] = src4[i];
  unsigned vb[7];
#pragma unroll
  for (int w2 = 0; w2 < 7; ++w2) vb[w2] = valid_bits[(size_t)g * 8 + w2];
  for (int e = tid; e < 400; e += 512) {
    unsigned cc = 0;
#pragma unroll
    for (int w2 = 0; w2 < 7; ++w2) cc += __popc(mfbits[e * 8 + w2] & vb[w2]);
    sInv[e] = 1.f / (float)max(cc, 1u);
    sHas[e] = (cc > 0) ? 1.f : 0.f;
  }
  __syncthreads();
  int w = tid >> 6, lane = tid & 63;
  const bf16x8* A = reinterpret_cast<const bf16x8*>(mfA);
  const bf16x8* Bb = reinterpret_cast<const bf16x8*>(sBf);
  for (int mt = w; mt < 25; mt += 8) {
    bf16x8 af[7];
#pragma unroll
    for (int kt = 0; kt < 7; ++kt) af[kt] = A[(mt * 7 + kt) * 64 + lane];
    f32x4 acc0 = {0.f, 0.f, 0.f, 0.f};
    f32x4 acc1 = {0.f, 0.f, 0.f, 0.f};
    f32x4 acc2 = {0.f, 0.f, 0.f, 0.f};
    f32x4 acc3 = {0.f, 0.f, 0.f, 0.f};
#pragma unroll
    for (int kt = 0; kt < 7; ++kt) {
      const bf16x8* B = Bb + kt * 256 + lane;
      acc0 = __builtin_amdgcn_mfma_f32_16x16x32_bf16(af[kt], B[0], acc0, 0, 0, 0);
      acc1 = __builtin_amdgcn_mfma_f32_16x16x32_bf16(af[kt], B[64], acc1, 0, 0, 0);
      acc2 = __builtin_amdgcn_mfma_f32_16x16x32_bf16(af[kt], B[128], acc2, 0, 0, 0);
      acc3 = __builtin_amdgcn_mfma_f32_16x16x32_bf16(af[kt], B[192], acc3, 0, 0, 0);
    }
    int rbase = mt * 16 + (lane >> 4) * 4;
    int col = lane & 15;
#pragma unroll
    for (int r = 0; r < 4; ++r) {
      int e = rbase + r;
      if (e >= n_edges) continue;
      float inv = sInv[e];
      float* gp = gmat + ((size_t)e * n_gt + g) * 64 + col;
      gp[0] = acc0[r] * inv;
      gp[16] = acc1[r] * inv;
      gp[32] = acc2[r] * inv;
      gp[48] = acc3[r] * inv;
      if (col == 0) has[(size_t)e * n_gt + g] = sHas[e];
    }
  }
}

// One block per species-tree edge: streaming mean/std over gene trees.
__global__ __launch_bounds__(512) void k_stat(const float* __restrict__ gmat,
                                              const float* __restrict__ has,
                                              float* __restrict__ out,
                                              int n_gt) {
  __shared__ float red1[8][64];
  __shared__ float red2[8][64];
  __shared__ float redn[8];
  int e = blockIdx.x;
  int tid = threadIdx.x, w = tid >> 6, lane = tid & 63;
  const float* ge = gmat + (size_t)e * n_gt * 64;
  const float* he = has + (size_t)e * n_gt;
  float S1 = 0.f, S2 = 0.f, nv = 0.f;
  for (int g = w; g < n_gt; g += 8) {
    float h = he[g];
    float v = ge[g * 64 + lane];
    S1 += h * v;
    S2 += h * v * v;
    nv += h;
  }
  red1[w][lane] = S1;
  red2[w][lane] = S2;
  if (lane == 0) redn[w] = nv;
  __syncthreads();
  if (w == 0) {
    float s1 = 0.f, s2 = 0.f, n_v = 0.f;
#pragma unroll
    for (int j = 0; j < 8; ++j) {
      s1 += red1[j][lane];
      s2 += red2[j][lane];
      n_v += redn[j];
    }
    float mean = s1 / fmaxf(n_v, 1.f);
    float var = (s2 - s1 * s1 / fmaxf(n_v, 1.f)) / fmaxf(n_v - 1.f, 1.f);
    float stdv = (n_v > 1.f) ? sqrtf(fmaxf(var, 0.f)) : 0.f;
    out[(size_t)e * 128 + lane] = (n_v > 0.f) ? mean : 0.f;
    out[(size_t)e * 128 + 64 + lane] = stdv;
  }
}

extern "C" void kernel_launch(void* const* d_in, const int* in_sizes, int n_in,
                              void* d_out, int out_size, void* d_ws, size_t ws_size,
                              hipStream_t stream) {
  (void)n_in; (void)out_size; (void)ws_size;
  const int* edge_index = (const int*)d_in[0];
  const int* sp_ids = (const int*)d_in[1];
  const int* leaf_mask = (const int*)d_in[2];
  const int* clade_mask = (const int*)d_in[4];
  const float* emb = (const float*)d_in[6];
  const float* W1 = (const float*)d_in[7];
  const float* b1 = (const float*)d_in[8];
  const float* W2 = (const float*)d_in[9];
  const float* b2 = (const float*)d_in[10];
  const float* eps = (const float*)d_in[11];
  const float* lng = (const float*)d_in[12];
  const float* lnb = (const float*)d_in[13];
  float* out = (float*)d_out;

  const int n_nodes = in_sizes[1];             // 204288
  const int nE = in_sizes[0] / 2;              // 407552 directed edges
  const int n_species = in_sizes[6] / 64 - 1;  // 200
  const int n_edges = in_sizes[4] / n_species; // 397
  const int L = in_sizes[11];                  // 2
  const int n_gt = 512;                        // fixed problem size
  const int npg = n_nodes / n_gt;              // 399 nodes per gene tree

  const int* src = edge_index;       // first half: child ids
  const int* dst = edge_index + nE;  // first half: parent ids

  float* x = (float*)d_ws;
  size_t xb = (size_t)n_nodes * 64 * sizeof(float);
  char* r1 = (char*)d_ws + xb;
  unsigned short* pool_swz = (unsigned short*)r1;
  size_t psz = (size_t)n_gt * 14336 * sizeof(unsigned short);
  unsigned* valid_bits = (unsigned*)(r1 + psz);
  size_t vbsz = (size_t)n_gt * 8 * sizeof(unsigned);
  unsigned short* mfA = (unsigned short*)(r1 + psz + vbsz);
  size_t masz = (size_t)25 * 7 * 512 * sizeof(unsigned short);
  unsigned* mfbits = (unsigned*)(r1 + psz + vbsz + masz);
  size_t mbsz = (size_t)400 * 8 * sizeof(unsigned);
  float* has = (float*)(r1 + psz + vbsz + masz + mbsz);
  float* gmat = x;  // x region reused after k_pool

  k_prep<<<64, 256, 0, stream>>>(clade_mask, mfA, mfbits, n_edges, n_species);

  for (int l = 0; l < L; ++l) {
    k_layer<<<n_gt, 512, 0, stream>>>(
        x, emb, sp_ids, src, dst, W1 + l * 4096, b1 + l * 64, W2 + l * 4096,
        b2 + l * 64, eps + l, lng + l * 64, lnb + l * 64, x, npg, n_species,
        (l == 0) ? 1 : 0);
  }

  k_pool<<<n_gt, 512, 0, stream>>>(x, sp_ids, leaf_mask, pool_swz, valid_bits,
                                   npg, n_species);
  k_gm2<<<n_gt, 512, 0, stream>>>(pool_swz, valid_bits, mfA, mfbits, gmat, has,
                                  n_edges, n_gt);
  k_stat<<<n_edges, 512, 0, stream>>>(gmat, has, out, n_gt);
}

// Round 10
// 192.494 us; speedup vs baseline: 45.7355x; 1.1443x over previous
//
#include <hip/hip_runtime.h>

// Fixed problem geometry: D=64, n_gt=512, npg=399 nodes/tree, 398 edges/tree.
#define SMAX 200
#define NPG 399

typedef __bf16 bf16x8 __attribute__((ext_vector_type(8)));
typedef _Float16 half8 __attribute__((ext_vector_type(8)));
typedef _Float16 half4v __attribute__((ext_vector_type(4)));
typedef float f32x4 __attribute__((ext_vector_type(4)));

__device__ __forceinline__ unsigned short f2bf(float f) {
  unsigned u = __float_as_uint(f);
  unsigned r = (u + 0x7FFFu + ((u >> 16) & 1u)) >> 16;
  return (unsigned short)r;
}

// Build A-operand fragments (mf as bf16, pre-swizzled into the 16x16x32 MFMA
// lane layout) and packed mf bitmasks.
__global__ __launch_bounds__(256) void k_prep(const int* __restrict__ clade,
                                              unsigned short* __restrict__ mfA,
                                              unsigned* __restrict__ mfbits,
                                              int n_edges, int n_species) {
  int stride = gridDim.x * 256;
  for (int idx = blockIdx.x * 256 + threadIdx.x; idx < 25 * 7 * 512;
       idx += stride) {
    int fi = idx >> 9, within = idx & 511;
    int mt = fi / 7, kt = fi % 7;
    int l = within >> 3, j = within & 7;
    int e = mt * 16 + (l & 15);
    int s = kt * 32 + ((l >> 4) & 3) * 8 + j;
    unsigned short v = 0;
    if (e < n_edges && s < n_species && clade[(size_t)e * n_species + s] != 0)
      v = 0x3F80;  // bf16(1.0)
    mfA[idx] = v;
  }
  for (int idx = blockIdx.x * 256 + threadIdx.x; idx < 400 * 8; idx += stride) {
    int e = idx >> 3, w = idx & 7;
    unsigned bits = 0;
    if (e < n_edges && w < 7) {
      for (int b = 0; b < 32; ++b) {
        int s = w * 32 + b;
        if (s < n_species && clade[(size_t)e * n_species + s] != 0)
          bits |= 1u << b;
      }
    }
    mfbits[idx] = bits;
  }
}

// Mega-kernel: one block per gene tree, 8 waves, x never touches HBM.
//  0: emb gather -> sA (f16), stage both layers' weights (frag-swizzled f16),
//     build child-CSR in LDS (hist -> scan -> scatter), reused by both layers.
//  1: GIN layer 0: sA -> sB   2: GIN layer 1: sB -> sA
//     (per-wave 16-node tiles: msg/u from x-lds -> XOR-swizzled f16 tile ->
//      MFMA1 -> relu -> MFMA2 -> residual+LN f32 -> f16 write)
//  3: species pooling: species-lists (CSR arrays reused) -> per-wave sums ->
//     bf16 frag-swizzled into sBf (aliased on dead sWf) + cnt/valid bits
//  4: clade-sum MFMA (mfA global x sBf) -> gmat, has.
// Fragment maps HW-verified rounds 6-7.
__global__ __launch_bounds__(512) void k_tree(
    const float* __restrict__ emb, const int* __restrict__ sp,
    const int* __restrict__ leaf, const int* __restrict__ src,
    const int* __restrict__ dst, const float* __restrict__ W1,
    const float* __restrict__ b1, const float* __restrict__ W2,
    const float* __restrict__ b2, const float* __restrict__ eps_p,
    const float* __restrict__ gam, const float* __restrict__ bet,
    const unsigned short* __restrict__ mfA, const unsigned* __restrict__ mfbits,
    float* __restrict__ gmat, float* __restrict__ has, int npg, int n_species,
    int n_edges, int n_gt) {
  __shared__ __attribute__((aligned(16))) _Float16 sA[NPG * 64];
  __shared__ __attribute__((aligned(16))) _Float16 sB[NPG * 64];
  __shared__ __attribute__((aligned(16))) _Float16 sWf[2][2][4096];
  __shared__ __attribute__((aligned(16))) _Float16 sT[8][1024];
  __shared__ int sStart[NPG + 1];
  __shared__ int sChild[NPG - 1];
  __shared__ int sPar[NPG];
  __shared__ int sCnt[NPG];

  int g = blockIdx.x, tid = threadIdx.x;
  int base = g * npg, nEt = npg - 1, ebase = g * nEt;
  int w = tid >> 6, lane = tid & 63;
  int cc = lane & 15, gq = lane >> 4;

  // ---- 0a: zero CSR counters
  for (int i = tid; i < npg + 1; i += 512) sStart[i] = 0;
  for (int i = tid; i < npg; i += 512) sCnt[i] = 0;
  __syncthreads();
  // ---- 0b: weights (both layers), emb gather, edges + histogram
  for (int idx = tid; idx < 4096; idx += 512) {
    int k = idx >> 6, n = idx & 63;
    int frag = (k >> 5) * 4 + (n >> 4);
    int ln = ((k >> 3) & 3) * 16 + (n & 15);
    int j = k & 7;
    int o = frag * 512 + ln * 8 + j;
    sWf[0][0][o] = (_Float16)W1[idx];
    sWf[0][1][o] = (_Float16)W2[idx];
    sWf[1][0][o] = (_Float16)W1[4096 + idx];
    sWf[1][1][o] = (_Float16)W2[4096 + idx];
  }
  for (int idx = tid; idx < npg * 16; idx += 512) {
    int node = idx >> 4, q = idx & 15;
    int s = sp[base + node];
    int row = (s < 0) ? n_species : s;
    float4 v = reinterpret_cast<const float4*>(emb)[row * 16 + q];
    half4v hv = {(_Float16)v.x, (_Float16)v.y, (_Float16)v.z, (_Float16)v.w};
    *reinterpret_cast<half4v*>(&sA[node * 64 + q * 4]) = hv;
  }
  for (int i = tid; i < nEt; i += 512) {
    int c = src[ebase + i] - base;
    int p = dst[ebase + i] - base;
    sPar[c] = p;
    atomicAdd(&sStart[p + 1], 1);
  }
  __syncthreads();
  // ---- 0c: inclusive scan -> child-region starts
  for (int off = 1; off < npg + 1; off <<= 1) {
    int t = 0;
    if (tid < npg + 1 && tid >= off) t = sStart[tid - off];
    __syncthreads();
    if (tid < npg + 1 && tid >= off) sStart[tid] += t;
    __syncthreads();
  }
  // ---- 0d: scatter children
  for (int c = tid + 1; c < npg; c += 512) {
    int p = sPar[c];
    int pos = sStart[p] + atomicAdd(&sCnt[p], 1);
    sChild[pos] = c;
  }
  __syncthreads();

  // ---- 1,2: GIN layers
  _Float16* tb = sT[w];
  for (int l = 0; l < 2; ++l) {
    const _Float16* xin = l ? sB : sA;
    _Float16* xout = l ? sA : sB;
    float e1 = 1.0f + eps_p[l];
    float b1v[4], b2v[4], gv[4], bv[4];
#pragma unroll
    for (int nt = 0; nt < 4; ++nt) {
      b1v[nt] = b1[l * 64 + cc + 16 * nt];
      b2v[nt] = b2[l * 64 + cc + 16 * nt];
      gv[nt] = gam[l * 64 + cc + 16 * nt];
      bv[nt] = bet[l * 64 + cc + 16 * nt];
    }
    const half8* B1 = reinterpret_cast<const half8*>(sWf[l][0]);
    const half8* B2 = reinterpret_cast<const half8*>(sWf[l][1]);
    for (int t = w; t < 25; t += 8) {
      int n0 = t * 16;
#pragma unroll 4
      for (int mm = 0; mm < 16; ++mm) {
        int node = n0 + mm;
        float u = 0.f;
        if (node < npg) {
          float s = 0.f;
          int j0 = sStart[node], j1 = sStart[node + 1];
          for (int j = j0; j < j1; ++j) s += (float)xin[sChild[j] * 64 + lane];
          if (node > 0) s += (float)xin[sPar[node] * 64 + lane];
          u = fmaf(e1, (float)xin[node * 64 + lane], s);
        }
        tb[mm * 64 + (lane ^ ((mm & 7) << 3))] = (_Float16)u;
      }
      int sw = (cc & 7) << 3;
      half8 a0 = *reinterpret_cast<const half8*>(&tb[cc * 64 + ((gq * 8) ^ sw)]);
      half8 a1 =
          *reinterpret_cast<const half8*>(&tb[cc * 64 + ((32 + gq * 8) ^ sw)]);
      f32x4 tacc[4];
#pragma unroll
      for (int nt = 0; nt < 4; ++nt) tacc[nt] = (f32x4){0.f, 0.f, 0.f, 0.f};
#pragma unroll
      for (int nt = 0; nt < 4; ++nt) {
        tacc[nt] = __builtin_amdgcn_mfma_f32_16x16x32_f16(
            a0, B1[nt * 64 + lane], tacc[nt], 0, 0, 0);
        tacc[nt] = __builtin_amdgcn_mfma_f32_16x16x32_f16(
            a1, B1[(4 + nt) * 64 + lane], tacc[nt], 0, 0, 0);
      }
#pragma unroll
      for (int nt = 0; nt < 4; ++nt)
#pragma unroll
        for (int r = 0; r < 4; ++r) {
          int m = gq * 4 + r;
          tb[m * 64 + ((cc + 16 * nt) ^ ((m & 7) << 3))] =
              (_Float16)fmaxf(tacc[nt][r] + b1v[nt], 0.f);
        }
      half8 c0 = *reinterpret_cast<const half8*>(&tb[cc * 64 + ((gq * 8) ^ sw)]);
      half8 c1 =
          *reinterpret_cast<const half8*>(&tb[cc * 64 + ((32 + gq * 8) ^ sw)]);
      f32x4 hacc[4];
#pragma unroll
      for (int nt = 0; nt < 4; ++nt) hacc[nt] = (f32x4){0.f, 0.f, 0.f, 0.f};
#pragma unroll
      for (int nt = 0; nt < 4; ++nt) {
        hacc[nt] = __builtin_amdgcn_mfma_f32_16x16x32_f16(
            c0, B2[nt * 64 + lane], hacc[nt], 0, 0, 0);
        hacc[nt] = __builtin_amdgcn_mfma_f32_16x16x32_f16(
            c1, B2[(4 + nt) * 64 + lane], hacc[nt], 0, 0, 0);
      }
      float y[4][4];
#pragma unroll
      for (int r = 0; r < 4; ++r) {
        int node = n0 + gq * 4 + r;
#pragma unroll
        for (int nt = 0; nt < 4; ++nt)
          y[r][nt] =
              ((node < npg) ? (float)xin[node * 64 + cc + 16 * nt] : 0.f) +
              hacc[nt][r] + b2v[nt];
      }
#pragma unroll
      for (int r = 0; r < 4; ++r) {
        float s = y[r][0] + y[r][1] + y[r][2] + y[r][3];
        s += __shfl_xor(s, 1);
        s += __shfl_xor(s, 2);
        s += __shfl_xor(s, 4);
        s += __shfl_xor(s, 8);
        float mu = s * (1.f / 64.f);
        float d0 = y[r][0] - mu, d1 = y[r][1] - mu;
        float d2 = y[r][2] - mu, d3 = y[r][3] - mu;
        float v = d0 * d0 + d1 * d1 + d2 * d2 + d3 * d3;
        v += __shfl_xor(v, 1);
        v += __shfl_xor(v, 2);
        v += __shfl_xor(v, 4);
        v += __shfl_xor(v, 8);
        float iv = rsqrtf(v * (1.f / 64.f) + 1e-5f);
        int node = n0 + gq * 4 + r;
        if (node < npg) {
#pragma unroll
          for (int nt = 0; nt < 4; ++nt)
            xout[node * 64 + cc + 16 * nt] =
                (_Float16)((y[r][nt] - mu) * iv * gv[nt] + bv[nt]);
        }
      }
    }
    __syncthreads();
  }

  // ---- 3a: re-zero for species lists; zero sBf (aliases dead weights)
  unsigned short* sBfU = reinterpret_cast<unsigned short*>(&sWf[0][0][0]);
  for (int i = tid; i < n_species + 1; i += 512) sStart[i] = 0;
  for (int i = tid; i < n_species; i += 512) sCnt[i] = 0;
  {
    float4 z4 = {0.f, 0.f, 0.f, 0.f};
    for (int i = tid; i < 1792; i += 512)
      reinterpret_cast<float4*>(sBfU)[i] = z4;
  }
  char* aux = reinterpret_cast<char*>(&sT[0][0]);  // sT dead after layers
  float* sInv = reinterpret_cast<float*>(aux);
  float* sHas = reinterpret_cast<float*>(aux + 1600);
  int* sSp = reinterpret_cast<int*>(aux + 3200);
  float* cntf = reinterpret_cast<float*>(aux + 4800);
  unsigned* svb = reinterpret_cast<unsigned*>(aux + 5632);
  __syncthreads();
  // ---- 3b: leaf species + histogram
  for (int i = tid; i < npg; i += 512) {
    int s = sp[base + i];
    bool v = (s >= 0) && (leaf[base + i] != 0);
    sSp[i] = v ? s : -1;
    if (v) atomicAdd(&sStart[s + 1], 1);
  }
  __syncthreads();
  // ---- 3c: scan over species
  for (int off = 1; off < n_species + 1; off <<= 1) {
    int t = 0;
    if (tid < n_species + 1 && tid >= off) t = sStart[tid - off];
    __syncthreads();
    if (tid < n_species + 1 && tid >= off) sStart[tid] += t;
    __syncthreads();
  }
  // ---- 3d: scatter node ids (spNode aliases sPar)
  for (int i = tid; i < npg; i += 512) {
    int s = sSp[i];
    if (s >= 0) {
      int pos = sStart[s] + atomicAdd(&sCnt[s], 1);
      sPar[pos] = i;
    }
  }
  __syncthreads();
  // ---- 3e: species means -> sBf (bf16 frag-swizzled) + counts
  for (int s = w; s < n_species; s += 8) {
    int j0 = sStart[s], j1 = sStart[s + 1];
    float sum = 0.f;
    for (int j = j0; j < j1; ++j) sum += (float)sA[sPar[j] * 64 + lane];
    float c = (float)(j1 - j0);
    float v = (c > 0.f) ? sum / c : 0.f;
    int frag = (s >> 5) * 4 + (lane >> 4);
    int ln = ((s >> 3) & 3) * 16 + (lane & 15);
    sBfU[frag * 512 + ln * 8 + (s & 7)] = f2bf(v);
    if (lane == 0) cntf[s] = c;
  }
  __syncthreads();
  // ---- 3f: valid bits, per-edge 1/ccnt + has
  if (tid < 7) {
    unsigned bits = 0;
    for (int b = 0; b < 32; ++b) {
      int s = tid * 32 + b;
      if (s < n_species && cntf[s] > 0.f) bits |= 1u << b;
    }
    svb[tid] = bits;
  }
  __syncthreads();
  for (int e = tid; e < 400; e += 512) {
    unsigned ccv = 0;
#pragma unroll
    for (int w2 = 0; w2 < 7; ++w2) ccv += __popc(mfbits[e * 8 + w2] & svb[w2]);
    sInv[e] = 1.f / (float)max(ccv, 1u);
    sHas[e] = (ccv > 0) ? 1.f : 0.f;
  }
  __syncthreads();
  // ---- 4: clade-sum MFMA -> gmat, has
  const bf16x8* A = reinterpret_cast<const bf16x8*>(mfA);
  const bf16x8* Bb = reinterpret_cast<const bf16x8*>(sBfU);
  for (int mt = w; mt < 25; mt += 8) {
    bf16x8 af[7];
#pragma unroll
    for (int kt = 0; kt < 7; ++kt) af[kt] = A[(mt * 7 + kt) * 64 + lane];
    f32x4 acc0 = {0.f, 0.f, 0.f, 0.f};
    f32x4 acc1 = {0.f, 0.f, 0.f, 0.f};
    f32x4 acc2 = {0.f, 0.f, 0.f, 0.f};
    f32x4 acc3 = {0.f, 0.f, 0.f, 0.f};
#pragma unroll
    for (int kt = 0; kt < 7; ++kt) {
      const bf16x8* B = Bb + kt * 256 + lane;
      acc0 = __builtin_amdgcn_mfma_f32_16x16x32_bf16(af[kt], B[0], acc0, 0, 0, 0);
      acc1 = __builtin_amdgcn_mfma_f32_16x16x32_bf16(af[kt], B[64], acc1, 0, 0, 0);
      acc2 = __builtin_amdgcn_mfma_f32_16x16x32_bf16(af[kt], B[128], acc2, 0, 0, 0);
      acc3 = __builtin_amdgcn_mfma_f32_16x16x32_bf16(af[kt], B[192], acc3, 0, 0, 0);
    }
    int rbase = mt * 16 + (lane >> 4) * 4;
    int col = lane & 15;
#pragma unroll
    for (int r = 0; r < 4; ++r) {
      int e = rbase + r;
      if (e >= n_edges) continue;
      float inv = sInv[e];
      float* gp = gmat + ((size_t)e * n_gt + g) * 64 + col;
      gp[0] = acc0[r] * inv;
      gp[16] = acc1[r] * inv;
      gp[32] = acc2[r] * inv;
      gp[48] = acc3[r] * inv;
      if (col == 0) has[(size_t)e * n_gt + g] = sHas[e];
    }
  }
}

// One block per species-tree edge: streaming mean/std over gene trees.
__global__ __launch_bounds__(512) void k_stat(const float* __restrict__ gmat,
                                              const float* __restrict__ has,
                                              float* __restrict__ out,
                                              int n_gt) {
  __shared__ float red1[8][64];
  __shared__ float red2[8][64];
  __shared__ float redn[8];
  int e = blockIdx.x;
  int tid = threadIdx.x, w = tid >> 6, lane = tid & 63;
  const float* ge = gmat + (size_t)e * n_gt * 64;
  const float* he = has + (size_t)e * n_gt;
  float S1 = 0.f, S2 = 0.f, nv = 0.f;
  for (int g = w; g < n_gt; g += 8) {
    float h = he[g];
    float v = ge[g * 64 + lane];
    S1 += h * v;
    S2 += h * v * v;
    nv += h;
  }
  red1[w][lane] = S1;
  red2[w][lane] = S2;
  if (lane == 0) redn[w] = nv;
  __syncthreads();
  if (w == 0) {
    float s1 = 0.f, s2 = 0.f, n_v = 0.f;
#pragma unroll
    for (int j = 0; j < 8; ++j) {
      s1 += red1[j][lane];
      s2 += red2[j][lane];
      n_v += redn[j];
    }
    float mean = s1 / fmaxf(n_v, 1.f);
    float var = (s2 - s1 * s1 / fmaxf(n_v, 1.f)) / fmaxf(n_v - 1.f, 1.f);
    float stdv = (n_v > 1.f) ? sqrtf(fmaxf(var, 0.f)) : 0.f;
    out[(size_t)e * 128 + lane] = (n_v > 0.f) ? mean : 0.f;
    out[(size_t)e * 128 + 64 + lane] = stdv;
  }
}

extern "C" void kernel_launch(void* const* d_in, const int* in_sizes, int n_in,
                              void* d_out, int out_size, void* d_ws, size_t ws_size,
                              hipStream_t stream) {
  (void)n_in; (void)out_size; (void)ws_size;
  const int* edge_index = (const int*)d_in[0];
  const int* sp_ids = (const int*)d_in[1];
  const int* leaf_mask = (const int*)d_in[2];
  const int* clade_mask = (const int*)d_in[4];
  const float* emb = (const float*)d_in[6];
  const float* W1 = (const float*)d_in[7];
  const float* b1 = (const float*)d_in[8];
  const float* W2 = (const float*)d_in[9];
  const float* b2 = (const float*)d_in[10];
  const float* eps = (const float*)d_in[11];
  const float* lng = (const float*)d_in[12];
  const float* lnb = (const float*)d_in[13];
  float* out = (float*)d_out;

  const int n_nodes = in_sizes[1];             // 204288
  const int nE = in_sizes[0] / 2;              // 407552 directed edges
  const int n_species = in_sizes[6] / 64 - 1;  // 200
  const int n_edges = in_sizes[4] / n_species; // 397
  const int n_gt = 512;                        // fixed problem size
  const int npg = n_nodes / n_gt;              // 399 nodes per gene tree

  const int* src = edge_index;       // first half: child ids
  const int* dst = edge_index + nE;  // first half: parent ids

  float* gmat = (float*)d_ws;
  size_t gsz = ((size_t)n_edges * n_gt * 64 * sizeof(float) + 255ul) & ~255ul;
  float* has = (float*)((char*)d_ws + gsz);
  size_t hsz = ((size_t)n_edges * n_gt * sizeof(float) + 255ul) & ~255ul;
  unsigned short* mfA = (unsigned short*)((char*)d_ws + gsz + hsz);
  size_t masz = ((size_t)25 * 7 * 512 * sizeof(unsigned short) + 255ul) & ~255ul;
  unsigned* mfbits = (unsigned*)((char*)d_ws + gsz + hsz + masz);

  k_prep<<<64, 256, 0, stream>>>(clade_mask, mfA, mfbits, n_edges, n_species);
  k_tree<<<n_gt, 512, 0, stream>>>(emb, sp_ids, leaf_mask, src, dst, W1, b1,
                                   W2, b2, eps, lng, lnb, mfA, mfbits, gmat,
                                   has, npg, n_species, n_edges, n_gt);
  k_stat<<<n_edges, 512, 0, stream>>>(gmat, has, out, n_gt);
}